// Round 3
// baseline (2599.525 us; speedup 1.0000x reference)
//
#include <hip/hip_runtime.h>
#include <hip/hip_bf16.h>
#include <math.h>

// VideoSwinBasicLayer: 2 swin blocks (W-MSA, SW-MSA) on (1,16,56,56,128), NH=4,
// window (8,7,7) -> L=392, nW=128, shift (4,3,3), HID=512.
// IO dtype: float32 (per reference setup_inputs). Tolerance is bf16-grade, so
// internal activations are bf16. Residual stream lives in d_out (f32, NTOK*128).
// ws: buf1 bf16 act 12.85MB + bufq bf16 qkv-chunk/hidden 19.3MB = 32.1MB.

#define NTOK 50176   // 16*56*56
#define CC   128
#define LL   392
#define NWIN 128
#define NHEAD 4
#define HDIM 32
#define QKSCALE 0.17677669529663687f  // 32^-0.5
#define LPAD 34      // u16 pad per k/v row (even -> 4B-aligned b32 reads)
#define WCHUNK 64    // windows per qkv/attn chunk
#define CROWS (WCHUNK*LL)  // 25088 rows per chunk

typedef unsigned short u16;
typedef unsigned int   u32;

__device__ __forceinline__ float b2f(u16 u){ return __uint_as_float(((u32)u)<<16); }
__device__ __forceinline__ float b2f_lo(u32 u){ return __uint_as_float(u<<16); }
__device__ __forceinline__ float b2f_hi(u32 u){ return __uint_as_float(u & 0xffff0000u); }
__device__ __forceinline__ u16 f2b(float f){
  __hip_bfloat16 h = __float2bfloat16(f);
  return *reinterpret_cast<u16*>(&h);
}

// window-ordered row r -> flat token position (gather source for LN1 and the
// scatter destination after attention; roll(+shift) in both directions).
__device__ __forceinline__ int row_to_pos(int r, int shifted){
  int w = r / LL, t = r - w*LL;
  int wd = w >> 6, wh = (w >> 3) & 7, ww = w & 7;
  int td = t / 49, rem = t - td*49, th = rem / 7, tw = rem - th*7;
  int d = wd*8 + td, h = wh*7 + th, x = ww*7 + tw;
  if (shifted){ d = (d+4)&15; h += 3; if (h>=56) h-=56; x += 3; if (x>=56) x-=56; }
  return (d*56 + h)*56 + x;
}

// LayerNorm over C=128 (f32 src), bf16 out. One wave per row.
__global__ __launch_bounds__(256) void ln_kernel(
    const float* __restrict__ xf, const float* __restrict__ g,
    const float* __restrict__ b, u16* __restrict__ out, int do_map, int shifted)
{
  int wave = threadIdx.x >> 6, lane = threadIdx.x & 63;
  int r = blockIdx.x*4 + wave;
  int pos = do_map ? row_to_pos(r, shifted) : r;
  long src = (long)pos * CC;
  float v0 = xf[src+lane], v1 = xf[src+64+lane];
  float s = v0+v1, ss = v0*v0 + v1*v1;
  #pragma unroll
  for (int o=32; o>0; o>>=1){ s += __shfl_xor(s,o); ss += __shfl_xor(ss,o); }
  float mean = s*(1.f/CC);
  float var  = ss*(1.f/CC) - mean*mean;
  float rstd = rsqrtf(var + 1e-5f);
  long dst = (long)r*CC;
  out[dst + lane]      = f2b((v0-mean)*rstd*g[lane]    + b[lane]);
  out[dst + 64 + lane] = f2b((v1-mean)*rstd*g[64+lane] + b[64+lane]);
}

// GEMM: Out[rows x M](bf16) = A[rows x K](bf16) @ Wt[K x M-slice](f32, stride ldw)
// + bias, opt exact GELU. 64x64 tile, 256 threads, 4x4 micro-tile, f32 accum.
template<int K, int M, int GELU>
__global__ __launch_bounds__(256) void gemm_rw_kernel(
    const u16* __restrict__ A, const float* __restrict__ Wt, int ldw,
    const float* __restrict__ bias, u16* __restrict__ Out)
{
  __shared__ float As[64][17];
  __shared__ float Bs[16][65];
  const int tid = threadIdx.x;
  const int tx = tid & 15, ty = tid >> 4;
  const int r0 = blockIdx.x * 64, n0 = blockIdx.y * 64;
  const int arow = tid >> 2,  acol = (tid & 3) << 2;
  const int brow = tid >> 4,  bcol = (tid & 15) << 2;
  float acc[4][4] = {};
  for (int k0 = 0; k0 < K; k0 += 16){
    uint2  av = *reinterpret_cast<const uint2*>(&A[(long)(r0+arow)*K + k0 + acol]);
    float4 wv = *reinterpret_cast<const float4*>(&Wt[(long)(k0+brow)*ldw + n0 + bcol]);
    As[arow][acol+0]=b2f_lo(av.x); As[arow][acol+1]=b2f_hi(av.x);
    As[arow][acol+2]=b2f_lo(av.y); As[arow][acol+3]=b2f_hi(av.y);
    Bs[brow][bcol+0]=wv.x; Bs[brow][bcol+1]=wv.y;
    Bs[brow][bcol+2]=wv.z; Bs[brow][bcol+3]=wv.w;
    __syncthreads();
    #pragma unroll
    for (int kk=0;kk<16;kk++){
      float a0=As[ty*4+0][kk], a1=As[ty*4+1][kk], a2=As[ty*4+2][kk], a3=As[ty*4+3][kk];
      float b0=Bs[kk][tx*4+0], b1=Bs[kk][tx*4+1], b2=Bs[kk][tx*4+2], b3=Bs[kk][tx*4+3];
      acc[0][0]=fmaf(a0,b0,acc[0][0]); acc[0][1]=fmaf(a0,b1,acc[0][1]);
      acc[0][2]=fmaf(a0,b2,acc[0][2]); acc[0][3]=fmaf(a0,b3,acc[0][3]);
      acc[1][0]=fmaf(a1,b0,acc[1][0]); acc[1][1]=fmaf(a1,b1,acc[1][1]);
      acc[1][2]=fmaf(a1,b2,acc[1][2]); acc[1][3]=fmaf(a1,b3,acc[1][3]);
      acc[2][0]=fmaf(a2,b0,acc[2][0]); acc[2][1]=fmaf(a2,b1,acc[2][1]);
      acc[2][2]=fmaf(a2,b2,acc[2][2]); acc[2][3]=fmaf(a2,b3,acc[2][3]);
      acc[3][0]=fmaf(a3,b0,acc[3][0]); acc[3][1]=fmaf(a3,b1,acc[3][1]);
      acc[3][2]=fmaf(a3,b2,acc[3][2]); acc[3][3]=fmaf(a3,b3,acc[3][3]);
    }
    __syncthreads();
  }
  #pragma unroll
  for (int i=0;i<4;i++){
    long r = r0 + ty*4 + i;
    #pragma unroll
    for (int j=0;j<4;j++){
      int c = n0 + tx*4 + j;
      float v = acc[i][j] + bias[c];
      if (GELU) v = 0.5f*v*(1.f + erff(v*0.70710678118654752f));
      Out[r*M + c] = f2b(v);
    }
  }
}

// proj GEMM (K=M=128) + window_reverse/roll-back scatter + residual -> f32 d_out.
__global__ __launch_bounds__(256) void gemm_proj_kernel(
    const u16* __restrict__ A, const float* __restrict__ Wt, const float* __restrict__ bias,
    const float* __restrict__ res, float* __restrict__ Out, int shifted)
{
  __shared__ float As[64][17];
  __shared__ float Bs[16][65];
  const int tid = threadIdx.x;
  const int tx = tid & 15, ty = tid >> 4;
  const int r0 = blockIdx.x * 64, n0 = blockIdx.y * 64;
  const int arow = tid >> 2,  acol = (tid & 3) << 2;
  const int brow = tid >> 4,  bcol = (tid & 15) << 2;
  float acc[4][4] = {};
  for (int k0 = 0; k0 < 128; k0 += 16){
    uint2  av = *reinterpret_cast<const uint2*>(&A[(long)(r0+arow)*128 + k0 + acol]);
    float4 wv = *reinterpret_cast<const float4*>(&Wt[(long)(k0+brow)*128 + n0 + bcol]);
    As[arow][acol+0]=b2f_lo(av.x); As[arow][acol+1]=b2f_hi(av.x);
    As[arow][acol+2]=b2f_lo(av.y); As[arow][acol+3]=b2f_hi(av.y);
    Bs[brow][bcol+0]=wv.x; Bs[brow][bcol+1]=wv.y;
    Bs[brow][bcol+2]=wv.z; Bs[brow][bcol+3]=wv.w;
    __syncthreads();
    #pragma unroll
    for (int kk=0;kk<16;kk++){
      float a0=As[ty*4+0][kk], a1=As[ty*4+1][kk], a2=As[ty*4+2][kk], a3=As[ty*4+3][kk];
      float b0=Bs[kk][tx*4+0], b1=Bs[kk][tx*4+1], b2=Bs[kk][tx*4+2], b3=Bs[kk][tx*4+3];
      acc[0][0]=fmaf(a0,b0,acc[0][0]); acc[0][1]=fmaf(a0,b1,acc[0][1]);
      acc[0][2]=fmaf(a0,b2,acc[0][2]); acc[0][3]=fmaf(a0,b3,acc[0][3]);
      acc[1][0]=fmaf(a1,b0,acc[1][0]); acc[1][1]=fmaf(a1,b1,acc[1][1]);
      acc[1][2]=fmaf(a1,b2,acc[1][2]); acc[1][3]=fmaf(a1,b3,acc[1][3]);
      acc[2][0]=fmaf(a2,b0,acc[2][0]); acc[2][1]=fmaf(a2,b1,acc[2][1]);
      acc[2][2]=fmaf(a2,b2,acc[2][2]); acc[2][3]=fmaf(a2,b3,acc[2][3]);
      acc[3][0]=fmaf(a3,b0,acc[3][0]); acc[3][1]=fmaf(a3,b1,acc[3][1]);
      acc[3][2]=fmaf(a3,b2,acc[3][2]); acc[3][3]=fmaf(a3,b3,acc[3][3]);
    }
    __syncthreads();
  }
  #pragma unroll
  for (int i=0;i<4;i++){
    int rr = r0 + ty*4 + i;
    long pos = (long)row_to_pos(rr, shifted) * CC;
    #pragma unroll
    for (int j=0;j<4;j++){
      int c = n0 + tx*4 + j;
      Out[pos + c] = res[pos + c] + acc[i][j] + bias[c];
    }
  }
}

// FC2 quarter GEMM (K=128 hidden slice): d_out[r,c] += A@Wt (+bias once).
__global__ __launch_bounds__(256) void gemm_fc2q_kernel(
    const u16* __restrict__ A, const float* __restrict__ Wt, const float* __restrict__ bias,
    float* __restrict__ acc_io, int use_bias)
{
  __shared__ float As[64][17];
  __shared__ float Bs[16][65];
  const int tid = threadIdx.x;
  const int tx = tid & 15, ty = tid >> 4;
  const int r0 = blockIdx.x * 64, n0 = blockIdx.y * 64;
  const int arow = tid >> 2,  acol = (tid & 3) << 2;
  const int brow = tid >> 4,  bcol = (tid & 15) << 2;
  float acc[4][4] = {};
  for (int k0 = 0; k0 < 128; k0 += 16){
    uint2  av = *reinterpret_cast<const uint2*>(&A[(long)(r0+arow)*128 + k0 + acol]);
    float4 wv = *reinterpret_cast<const float4*>(&Wt[(long)(k0+brow)*128 + n0 + bcol]);
    As[arow][acol+0]=b2f_lo(av.x); As[arow][acol+1]=b2f_hi(av.x);
    As[arow][acol+2]=b2f_lo(av.y); As[arow][acol+3]=b2f_hi(av.y);
    Bs[brow][bcol+0]=wv.x; Bs[brow][bcol+1]=wv.y;
    Bs[brow][bcol+2]=wv.z; Bs[brow][bcol+3]=wv.w;
    __syncthreads();
    #pragma unroll
    for (int kk=0;kk<16;kk++){
      float a0=As[ty*4+0][kk], a1=As[ty*4+1][kk], a2=As[ty*4+2][kk], a3=As[ty*4+3][kk];
      float b0=Bs[kk][tx*4+0], b1=Bs[kk][tx*4+1], b2=Bs[kk][tx*4+2], b3=Bs[kk][tx*4+3];
      acc[0][0]=fmaf(a0,b0,acc[0][0]); acc[0][1]=fmaf(a0,b1,acc[0][1]);
      acc[0][2]=fmaf(a0,b2,acc[0][2]); acc[0][3]=fmaf(a0,b3,acc[0][3]);
      acc[1][0]=fmaf(a1,b0,acc[1][0]); acc[1][1]=fmaf(a1,b1,acc[1][1]);
      acc[1][2]=fmaf(a1,b2,acc[1][2]); acc[1][3]=fmaf(a1,b3,acc[1][3]);
      acc[2][0]=fmaf(a2,b0,acc[2][0]); acc[2][1]=fmaf(a2,b1,acc[2][1]);
      acc[2][2]=fmaf(a2,b2,acc[2][2]); acc[2][3]=fmaf(a2,b3,acc[2][3]);
      acc[3][0]=fmaf(a3,b0,acc[3][0]); acc[3][1]=fmaf(a3,b1,acc[3][1]);
      acc[3][2]=fmaf(a3,b2,acc[3][2]); acc[3][3]=fmaf(a3,b3,acc[3][3]);
    }
    __syncthreads();
  }
  #pragma unroll
  for (int i=0;i<4;i++){
    long r = r0 + ty*4 + i;
    #pragma unroll
    for (int j=0;j<4;j++){
      int c = n0 + tx*4 + j;
      float v = acc_io[r*CC + c] + acc[i][j];
      if (use_bias) v += bias[c];
      acc_io[r*CC + c] = v;
    }
  }
}

// Attention: one block per (chunk-local window, head). k/v bf16 in LDS; per-wave
// query rows; rel-pos-bias gathered from global (f32); region mask arithmetic.
__global__ __launch_bounds__(256) void attn_kernel(
    const u16* __restrict__ qkv, const float* __restrict__ rpb,
    u16* __restrict__ out, int shifted, int wbase)
{
  __shared__ u16 kS[LL*LPAD];
  __shared__ u16 vS[LL*LPAD];
  __shared__ float pS[4][LL];

  const int lw = blockIdx.x >> 2, head = blockIdx.x & 3;
  const int w = wbase + lw;
  const int tid = threadIdx.x, lane = tid & 63, wave = tid >> 6;
  const long qkvbase = (long)lw * LL * 384;
  const int wd = w>>6, wh = (w>>3)&7, ww = w&7;

  for (int idx = tid; idx < LL*32; idx += 256){
    int j = idx >> 5, d = idx & 31;
    long o = qkvbase + (long)j*384 + head*HDIM + d;
    kS[j*LPAD + d] = f2b(qkv[o + 128] == 0 ? 0.f : b2f(qkv[o + 128]));
    kS[j*LPAD + d] = qkv[o + 128];
    vS[j*LPAD + d] = qkv[o + 256];
  }
  __syncthreads();

  // per-lane key-token precompute: j = jt*64+lane fixed across rows.
  int cj[7]; int regj[7];
  #pragma unroll
  for (int jt=0;jt<7;jt++){
    int j = jt*64 + lane;
    if (j < LL){
      int td=j/49, rem=j-td*49, th=rem/7, tw=rem-th*7;
      cj[jt] = td*169 + th*13 + tw;
      int dr = (wd==0)?0:((td<4)?1:2);
      int hr = (wh<7)?0:((th<4)?1:2);
      int wr = (ww<7)?0:((tw<4)?1:2);
      regj[jt] = dr*9 + hr*3 + wr;
    } else { cj[jt]=0; regj[jt]=0; }
  }

  for (int i = wave; i < LL; i += 4){
    int tdi = i/49, rem = i - tdi*49, thi = rem/7, twi = rem - thi*7;
    int basei = tdi*169 + thi*13 + twi + 1267;  // rel idx = basei - cj
    int dri = (wd==0)?0:((tdi<4)?1:2);
    int hri = (wh<7)?0:((thi<4)?1:2);
    int wri = (ww<7)?0:((twi<4)?1:2);
    int regi = dri*9 + hri*3 + wri;
    float q[32];
    const u16* qp = &qkv[qkvbase + (long)i*384 + head*HDIM];
    #pragma unroll
    for (int d=0; d<32; d++) q[d] = b2f(qp[d]) * QKSCALE;

    float sv[7];
    float smax = -1e30f;
    #pragma unroll
    for (int jt=0;jt<7;jt++){
      int j = jt*64 + lane;
      float s = -1e30f;
      if (j < LL){
        const u16* kp = &kS[j*LPAD];
        float dot = 0.f;
        #pragma unroll
        for (int d2=0; d2<16; d2++){
          u32 pk = *reinterpret_cast<const u32*>(kp + d2*2);
          dot = fmaf(q[2*d2],   b2f_lo(pk), dot);
          dot = fmaf(q[2*d2+1], b2f_hi(pk), dot);
        }
        s = dot + rpb[(basei - cj[jt])*NHEAD + head];
        if (shifted && (regj[jt] != regi)) s -= 100.f;
      }
      sv[jt] = s;
      smax = fmaxf(smax, s);
    }
    #pragma unroll
    for (int o=32;o>0;o>>=1) smax = fmaxf(smax, __shfl_xor(smax, o));
    float ssum = 0.f;
    #pragma unroll
    for (int jt=0;jt<7;jt++){
      int j = jt*64 + lane;
      if (j < LL){
        float p = expf(sv[jt] - smax);
        pS[wave][j] = p;
        ssum += p;
      }
    }
    #pragma unroll
    for (int o=32;o>0;o>>=1) ssum += __shfl_xor(ssum, o);
    float inv = 1.f / ssum;

    const int dl = (lane & 15)*2;   // dim pair
    const int jq = lane >> 4;       // j-quarter
    float o0=0.f, o1=0.f;
    const int jb = jq*98;
    for (int j=jb; j<jb+98; j++){
      float p = pS[wave][j];
      u32 pv = *reinterpret_cast<const u32*>(&vS[j*LPAD + dl]);
      o0 = fmaf(p, b2f_lo(pv), o0);
      o1 = fmaf(p, b2f_hi(pv), o1);
    }
    o0 += __shfl_xor(o0, 16); o1 += __shfl_xor(o1, 16);
    o0 += __shfl_xor(o0, 32); o1 += __shfl_xor(o1, 32);
    if (lane < 16){
      u32 pack = (u32)f2b(o0*inv) | ((u32)f2b(o1*inv) << 16);
      *reinterpret_cast<u32*>(&out[((long)(w*LL + i))*CC + head*HDIM + dl]) = pack;
    }
  }
}

extern "C" void kernel_launch(void* const* d_in, const int* in_sizes, int n_in,
                              void* d_out, int out_size, void* d_ws, size_t ws_size,
                              hipStream_t stream)
{
  const float* x     = (const float*)d_in[0];
  const float* ln1g  = (const float*)d_in[1];
  const float* ln1b  = (const float*)d_in[2];
  const float* qkvw  = (const float*)d_in[3];
  const float* qkvb  = (const float*)d_in[4];
  const float* rpb   = (const float*)d_in[5];
  const float* projw = (const float*)d_in[6];
  const float* projb = (const float*)d_in[7];
  const float* ln2g  = (const float*)d_in[8];
  const float* ln2b  = (const float*)d_in[9];
  const float* fc1w  = (const float*)d_in[10];
  const float* fc1b  = (const float*)d_in[11];
  const float* fc2w  = (const float*)d_in[12];
  const float* fc2b  = (const float*)d_in[13];
  float* outf = (float*)d_out;           // residual stream lives here (f32)

  u16* buf1 = (u16*)d_ws;                               // bf16 activations, NTOK*128
  u16* bufq = buf1 + (size_t)NTOK*CC;                   // bf16 qkv chunk / mlp hidden

  for (int blk = 0; blk < 2; ++blk){
    const int sh = blk;
    const float* resid = (blk==0) ? x : outf;
    // LN1 + roll + window-partition gather (reads f32 resid)
    ln_kernel<<<NTOK/4, 256, 0, stream>>>(resid,
        ln1g + blk*CC, ln1b + blk*CC, buf1, 1, sh);
    // QKV + attention in 2 window-chunks of 64
    for (int c = 0; c < 2; ++c){
      gemm_rw_kernel<128,384,0><<<dim3(CROWS/64, 6), 256, 0, stream>>>(
          buf1 + (size_t)c*CROWS*CC, qkvw + (size_t)blk*128*384, 384,
          qkvb + blk*384, bufq);
      attn_kernel<<<WCHUNK*NHEAD, 256, 0, stream>>>(
          bufq, rpb + (size_t)blk*2535*NHEAD, buf1, sh, c*WCHUNK);
    }
    // proj + reverse/roll-back scatter + residual -> d_out (f32)
    gemm_proj_kernel<<<dim3(NTOK/64, 2), 256, 0, stream>>>(
        buf1, projw + (size_t)blk*128*128, projb + blk*CC, resid, outf, sh);
    // LN2 (reads d_out)
    ln_kernel<<<NTOK/4, 256, 0, stream>>>(outf,
        ln2g + blk*CC, ln2b + blk*CC, buf1, 0, 0);
    // MLP in 4 column-quarters of 128; hidden quarter reuses bufq region
    for (int q = 0; q < 4; ++q){
      gemm_rw_kernel<128,128,1><<<dim3(NTOK/64, 2), 256, 0, stream>>>(
          buf1, fc1w + (size_t)blk*128*512 + q*128, 512,
          fc1b + blk*512 + q*128, bufq);
      gemm_fc2q_kernel<<<dim3(NTOK/64, 2), 256, 0, stream>>>(
          bufq, fc2w + (size_t)blk*512*128 + (size_t)q*128*128,
          fc2b + blk*CC, outf, q==0 ? 1 : 0);
    }
  }
}

// Round 4
// 1581.667 us; speedup vs baseline: 1.6435x; 1.6435x over previous
//
#include <hip/hip_runtime.h>
#include <hip/hip_bf16.h>
#include <math.h>

// VideoSwinBasicLayer: 2 swin blocks (W-MSA, SW-MSA) on (1,16,56,56,128), NH=4,
// window (8,7,7) -> L=392, nW=128, shift (4,3,3), HID=512.
// IO dtype: float32. Internal activations bf16 (tolerance is bf16-grade).
// Residual stream lives in d_out (f32). ws: buf1 bf16 12.85MB + bufq 19.3MB.
// R4: attention rewritten as MFMA flash (16x16x32 bf16, online softmax).

#define NTOK 50176   // 16*56*56
#define CC   128
#define LL   392
#define NWIN 128
#define NHEAD 4
#define HDIM 32
#define QKSCALE 0.17677669529663687f  // 32^-0.5
#define WCHUNK 64    // windows per qkv/attn chunk
#define CROWS (WCHUNK*LL)  // 25088 rows per chunk

// attention LDS layout (u16 units)
#define KSTRIDE 40            // 32 dims + pad (80B rows: 16B-aligned, 2-way banks)
#define KOFF    0             // K: 416 x KSTRIDE            = 16640 u16
#define VSTRIDE 424           // keys + pad (848B rows: 16B-aligned)
#define VOFF    16640         // V_T: 32 x VSTRIDE           = 13568 u16
#define POFF    30208         // P: 4 waves x 16 x 32        = 2048 u16
#define LDS_U16 32256         // total 64512 B

typedef unsigned short u16;
typedef unsigned int   u32;
typedef __attribute__((ext_vector_type(8))) short short8;
typedef __attribute__((ext_vector_type(4))) float f32x4;

__device__ __forceinline__ float b2f(u16 u){ return __uint_as_float(((u32)u)<<16); }
__device__ __forceinline__ float b2f_lo(u32 u){ return __uint_as_float(u<<16); }
__device__ __forceinline__ float b2f_hi(u32 u){ return __uint_as_float(u & 0xffff0000u); }
__device__ __forceinline__ u16 f2b(float f){
  __hip_bfloat16 h = __float2bfloat16(f);
  return *reinterpret_cast<u16*>(&h);
}

// window-ordered row r -> flat token position (gather source for LN1 and the
// scatter destination after attention; roll(+shift) in both directions).
__device__ __forceinline__ int row_to_pos(int r, int shifted){
  int w = r / LL, t = r - w*LL;
  int wd = w >> 6, wh = (w >> 3) & 7, ww = w & 7;
  int td = t / 49, rem = t - td*49, th = rem / 7, tw = rem - th*7;
  int d = wd*8 + td, h = wh*7 + th, x = ww*7 + tw;
  if (shifted){ d = (d+4)&15; h += 3; if (h>=56) h-=56; x += 3; if (x>=56) x-=56; }
  return (d*56 + h)*56 + x;
}

// LayerNorm over C=128 (f32 src), bf16 out. One wave per row.
__global__ __launch_bounds__(256) void ln_kernel(
    const float* __restrict__ xf, const float* __restrict__ g,
    const float* __restrict__ b, u16* __restrict__ out, int do_map, int shifted)
{
  int wave = threadIdx.x >> 6, lane = threadIdx.x & 63;
  int r = blockIdx.x*4 + wave;
  int pos = do_map ? row_to_pos(r, shifted) : r;
  long src = (long)pos * CC;
  float v0 = xf[src+lane], v1 = xf[src+64+lane];
  float s = v0+v1, ss = v0*v0 + v1*v1;
  #pragma unroll
  for (int o=32; o>0; o>>=1){ s += __shfl_xor(s,o); ss += __shfl_xor(ss,o); }
  float mean = s*(1.f/CC);
  float var  = ss*(1.f/CC) - mean*mean;
  float rstd = rsqrtf(var + 1e-5f);
  long dst = (long)r*CC;
  out[dst + lane]      = f2b((v0-mean)*rstd*g[lane]    + b[lane]);
  out[dst + 64 + lane] = f2b((v1-mean)*rstd*g[64+lane] + b[64+lane]);
}

// GEMM: Out[rows x M](bf16) = A[rows x K](bf16) @ Wt[K x M-slice](f32, stride ldw)
// + bias, opt exact GELU. 64x64 tile, 256 threads, 4x4 micro-tile, f32 accum.
template<int K, int M, int GELU>
__global__ __launch_bounds__(256) void gemm_rw_kernel(
    const u16* __restrict__ A, const float* __restrict__ Wt, int ldw,
    const float* __restrict__ bias, u16* __restrict__ Out)
{
  __shared__ float As[64][17];
  __shared__ float Bs[16][65];
  const int tid = threadIdx.x;
  const int tx = tid & 15, ty = tid >> 4;
  const int r0 = blockIdx.x * 64, n0 = blockIdx.y * 64;
  const int arow = tid >> 2,  acol = (tid & 3) << 2;
  const int brow = tid >> 4,  bcol = (tid & 15) << 2;
  float acc[4][4] = {};
  for (int k0 = 0; k0 < K; k0 += 16){
    uint2  av = *reinterpret_cast<const uint2*>(&A[(long)(r0+arow)*K + k0 + acol]);
    float4 wv = *reinterpret_cast<const float4*>(&Wt[(long)(k0+brow)*ldw + n0 + bcol]);
    As[arow][acol+0]=b2f_lo(av.x); As[arow][acol+1]=b2f_hi(av.x);
    As[arow][acol+2]=b2f_lo(av.y); As[arow][acol+3]=b2f_hi(av.y);
    Bs[brow][bcol+0]=wv.x; Bs[brow][bcol+1]=wv.y;
    Bs[brow][bcol+2]=wv.z; Bs[brow][bcol+3]=wv.w;
    __syncthreads();
    #pragma unroll
    for (int kk=0;kk<16;kk++){
      float a0=As[ty*4+0][kk], a1=As[ty*4+1][kk], a2=As[ty*4+2][kk], a3=As[ty*4+3][kk];
      float b0=Bs[kk][tx*4+0], b1=Bs[kk][tx*4+1], b2=Bs[kk][tx*4+2], b3=Bs[kk][tx*4+3];
      acc[0][0]=fmaf(a0,b0,acc[0][0]); acc[0][1]=fmaf(a0,b1,acc[0][1]);
      acc[0][2]=fmaf(a0,b2,acc[0][2]); acc[0][3]=fmaf(a0,b3,acc[0][3]);
      acc[1][0]=fmaf(a1,b0,acc[1][0]); acc[1][1]=fmaf(a1,b1,acc[1][1]);
      acc[1][2]=fmaf(a1,b2,acc[1][2]); acc[1][3]=fmaf(a1,b3,acc[1][3]);
      acc[2][0]=fmaf(a2,b0,acc[2][0]); acc[2][1]=fmaf(a2,b1,acc[2][1]);
      acc[2][2]=fmaf(a2,b2,acc[2][2]); acc[2][3]=fmaf(a2,b3,acc[2][3]);
      acc[3][0]=fmaf(a3,b0,acc[3][0]); acc[3][1]=fmaf(a3,b1,acc[3][1]);
      acc[3][2]=fmaf(a3,b2,acc[3][2]); acc[3][3]=fmaf(a3,b3,acc[3][3]);
    }
    __syncthreads();
  }
  #pragma unroll
  for (int i=0;i<4;i++){
    long r = r0 + ty*4 + i;
    #pragma unroll
    for (int j=0;j<4;j++){
      int c = n0 + tx*4 + j;
      float v = acc[i][j] + bias[c];
      if (GELU) v = 0.5f*v*(1.f + erff(v*0.70710678118654752f));
      Out[r*M + c] = f2b(v);
    }
  }
}

// proj GEMM (K=M=128) + window_reverse/roll-back scatter + residual -> f32 d_out.
__global__ __launch_bounds__(256) void gemm_proj_kernel(
    const u16* __restrict__ A, const float* __restrict__ Wt, const float* __restrict__ bias,
    const float* __restrict__ res, float* __restrict__ Out, int shifted)
{
  __shared__ float As[64][17];
  __shared__ float Bs[16][65];
  const int tid = threadIdx.x;
  const int tx = tid & 15, ty = tid >> 4;
  const int r0 = blockIdx.x * 64, n0 = blockIdx.y * 64;
  const int arow = tid >> 2,  acol = (tid & 3) << 2;
  const int brow = tid >> 4,  bcol = (tid & 15) << 2;
  float acc[4][4] = {};
  for (int k0 = 0; k0 < 128; k0 += 16){
    uint2  av = *reinterpret_cast<const uint2*>(&A[(long)(r0+arow)*128 + k0 + acol]);
    float4 wv = *reinterpret_cast<const float4*>(&Wt[(long)(k0+brow)*128 + n0 + bcol]);
    As[arow][acol+0]=b2f_lo(av.x); As[arow][acol+1]=b2f_hi(av.x);
    As[arow][acol+2]=b2f_lo(av.y); As[arow][acol+3]=b2f_hi(av.y);
    Bs[brow][bcol+0]=wv.x; Bs[brow][bcol+1]=wv.y;
    Bs[brow][bcol+2]=wv.z; Bs[brow][bcol+3]=wv.w;
    __syncthreads();
    #pragma unroll
    for (int kk=0;kk<16;kk++){
      float a0=As[ty*4+0][kk], a1=As[ty*4+1][kk], a2=As[ty*4+2][kk], a3=As[ty*4+3][kk];
      float b0=Bs[kk][tx*4+0], b1=Bs[kk][tx*4+1], b2=Bs[kk][tx*4+2], b3=Bs[kk][tx*4+3];
      acc[0][0]=fmaf(a0,b0,acc[0][0]); acc[0][1]=fmaf(a0,b1,acc[0][1]);
      acc[0][2]=fmaf(a0,b2,acc[0][2]); acc[0][3]=fmaf(a0,b3,acc[0][3]);
      acc[1][0]=fmaf(a1,b0,acc[1][0]); acc[1][1]=fmaf(a1,b1,acc[1][1]);
      acc[1][2]=fmaf(a1,b2,acc[1][2]); acc[1][3]=fmaf(a1,b3,acc[1][3]);
      acc[2][0]=fmaf(a2,b0,acc[2][0]); acc[2][1]=fmaf(a2,b1,acc[2][1]);
      acc[2][2]=fmaf(a2,b2,acc[2][2]); acc[2][3]=fmaf(a2,b3,acc[2][3]);
      acc[3][0]=fmaf(a3,b0,acc[3][0]); acc[3][1]=fmaf(a3,b1,acc[3][1]);
      acc[3][2]=fmaf(a3,b2,acc[3][2]); acc[3][3]=fmaf(a3,b3,acc[3][3]);
    }
    __syncthreads();
  }
  #pragma unroll
  for (int i=0;i<4;i++){
    int rr = r0 + ty*4 + i;
    long pos = (long)row_to_pos(rr, shifted) * CC;
    #pragma unroll
    for (int j=0;j<4;j++){
      int c = n0 + tx*4 + j;
      Out[pos + c] = res[pos + c] + acc[i][j] + bias[c];
    }
  }
}

// FC2 quarter GEMM (K=128 hidden slice): d_out[r,c] += A@Wt (+bias once).
__global__ __launch_bounds__(256) void gemm_fc2q_kernel(
    const u16* __restrict__ A, const float* __restrict__ Wt, const float* __restrict__ bias,
    float* __restrict__ acc_io, int use_bias)
{
  __shared__ float As[64][17];
  __shared__ float Bs[16][65];
  const int tid = threadIdx.x;
  const int tx = tid & 15, ty = tid >> 4;
  const int r0 = blockIdx.x * 64, n0 = blockIdx.y * 64;
  const int arow = tid >> 2,  acol = (tid & 3) << 2;
  const int brow = tid >> 4,  bcol = (tid & 15) << 2;
  float acc[4][4] = {};
  for (int k0 = 0; k0 < 128; k0 += 16){
    uint2  av = *reinterpret_cast<const uint2*>(&A[(long)(r0+arow)*128 + k0 + acol]);
    float4 wv = *reinterpret_cast<const float4*>(&Wt[(long)(k0+brow)*128 + n0 + bcol]);
    As[arow][acol+0]=b2f_lo(av.x); As[arow][acol+1]=b2f_hi(av.x);
    As[arow][acol+2]=b2f_lo(av.y); As[arow][acol+3]=b2f_hi(av.y);
    Bs[brow][bcol+0]=wv.x; Bs[brow][bcol+1]=wv.y;
    Bs[brow][bcol+2]=wv.z; Bs[brow][bcol+3]=wv.w;
    __syncthreads();
    #pragma unroll
    for (int kk=0;kk<16;kk++){
      float a0=As[ty*4+0][kk], a1=As[ty*4+1][kk], a2=As[ty*4+2][kk], a3=As[ty*4+3][kk];
      float b0=Bs[kk][tx*4+0], b1=Bs[kk][tx*4+1], b2=Bs[kk][tx*4+2], b3=Bs[kk][tx*4+3];
      acc[0][0]=fmaf(a0,b0,acc[0][0]); acc[0][1]=fmaf(a0,b1,acc[0][1]);
      acc[0][2]=fmaf(a0,b2,acc[0][2]); acc[0][3]=fmaf(a0,b3,acc[0][3]);
      acc[1][0]=fmaf(a1,b0,acc[1][0]); acc[1][1]=fmaf(a1,b1,acc[1][1]);
      acc[1][2]=fmaf(a1,b2,acc[1][2]); acc[1][3]=fmaf(a1,b3,acc[1][3]);
      acc[2][0]=fmaf(a2,b0,acc[2][0]); acc[2][1]=fmaf(a2,b1,acc[2][1]);
      acc[2][2]=fmaf(a2,b2,acc[2][2]); acc[2][3]=fmaf(a2,b3,acc[2][3]);
      acc[3][0]=fmaf(a3,b0,acc[3][0]); acc[3][1]=fmaf(a3,b1,acc[3][1]);
      acc[3][2]=fmaf(a3,b2,acc[3][2]); acc[3][3]=fmaf(a3,b3,acc[3][3]);
    }
    __syncthreads();
  }
  #pragma unroll
  for (int i=0;i<4;i++){
    long r = r0 + ty*4 + i;
    #pragma unroll
    for (int j=0;j<4;j++){
      int c = n0 + tx*4 + j;
      float v = acc_io[r*CC + c] + acc[i][j];
      if (use_bias) v += bias[c];
      acc_io[r*CC + c] = v;
    }
  }
}

// MFMA flash attention. One block per (chunk-local window, head); 4 waves, each
// owns 16-row query tiles (qt = wave, wave+4, ...). K [416xKSTRIDE] and V^T
// [32xVSTRIDE] bf16 in LDS; 32-key steps: QK = 2x mfma_16x16x32_bf16 (K=32=hd),
// online softmax in C-layout frags, P via wave-private LDS (C->A layout), PV =
// 2x mfma. Bias rpb gathered from global; region mask arithmetic.
__global__ __launch_bounds__(256) void attn_kernel(
    const u16* __restrict__ qkv, const float* __restrict__ rpbp,
    u16* __restrict__ out, int shifted, int wbase)
{
  __shared__ __align__(16) u16 lds[LDS_U16];

  const int lw = blockIdx.x >> 2, head = blockIdx.x & 3;
  const int w = wbase + lw;
  const int tid = threadIdx.x, lane = tid & 63, wave = tid >> 6;
  const int quad = lane >> 4, l15 = lane & 15;
  const long qkvbase = (long)lw * LL * 384;
  const int wd = w>>6, wh = (w>>3)&7, ww = w&7;
  const int pbase = POFF + wave*512;   // 16 rows x 32 cols

  // stage K (rows 392..415 zeroed)
  for (int idx = tid; idx < 416*4; idx += 256){
    int key = idx >> 2, part = idx & 3;
    short8 val = {0,0,0,0,0,0,0,0};
    if (key < LL)
      val = *reinterpret_cast<const short8*>(&qkv[qkvbase + (long)key*384 + 128 + head*HDIM + part*8]);
    *reinterpret_cast<short8*>(&lds[KOFF + key*KSTRIDE + part*8]) = val;
  }
  // stage V transposed (keys 392..415 zeroed)
  for (int idx = tid; idx < 416*32; idx += 256){
    int key = idx >> 5, d = idx & 31;
    u16 v = (key < LL) ? qkv[qkvbase + (long)key*384 + 256 + head*HDIM + d] : (u16)0;
    lds[VOFF + d*VSTRIDE + key] = v;
  }
  __syncthreads();

  for (int qt = wave; qt < 25; qt += 4){
    int qrow = qt*16 + l15; if (qrow > LL-1) qrow = LL-1;
    short8 qf = *reinterpret_cast<const short8*>(&qkv[qkvbase + (long)qrow*384 + head*HDIM + quad*8]);

    float m_r[4], l_r[4];
    int basei[4], regi[4];
    #pragma unroll
    for (int r=0;r<4;r++){
      int i = qt*16 + quad*4 + r; if (i > LL-1) i = LL-1;
      int td = i/49, rm = i - td*49, th = rm/7, tw = rm - th*7;
      basei[r] = td*169 + th*13 + tw + 1267;
      int dr = (wd==0)?0:((td<4)?1:2);
      int hr = (wh<7)?0:((th<4)?1:2);
      int wr = (ww<7)?0:((tw<4)?1:2);
      regi[r] = dr*9 + hr*3 + wr;
      m_r[r] = -1e30f; l_r[r] = 0.f;
    }
    f32x4 oc0 = {0.f,0.f,0.f,0.f}, oc1 = {0.f,0.f,0.f,0.f};

    for (int s = 0; s < 13; s++){
      const int kbase = s*32;
      short8 kf0 = *reinterpret_cast<const short8*>(&lds[KOFF + (kbase + l15)*KSTRIDE + quad*8]);
      short8 kf1 = *reinterpret_cast<const short8*>(&lds[KOFF + (kbase + 16 + l15)*KSTRIDE + quad*8]);
      f32x4 z = {0.f,0.f,0.f,0.f};
      f32x4 c0 = __builtin_amdgcn_mfma_f32_16x16x32_bf16(qf, kf0, z, 0,0,0);
      f32x4 c1 = __builtin_amdgcn_mfma_f32_16x16x32_bf16(qf, kf1, z, 0,0,0);

      // key-column coords (2 cols per lane)
      int j0 = kbase + l15, j1 = j0 + 16;
      int jd0 = j0/49, jr0 = j0 - jd0*49, jh0 = jr0/7, jw0 = jr0 - jh0*7;
      int jd1 = j1/49, jr1 = j1 - jd1*49, jh1 = jr1/7, jw1 = jr1 - jh1*7;
      int cj0 = jd0*169 + jh0*13 + jw0;
      int cj1 = jd1*169 + jh1*13 + jw1;
      int regj0 = ((wd==0)?0:((jd0<4)?1:2))*9 + ((wh<7)?0:((jh0<4)?1:2))*3 + ((ww<7)?0:((jw0<4)?1:2));
      int regj1 = ((wd==0)?0:((jd1<4)?1:2))*9 + ((wh<7)?0:((jh1<4)?1:2))*3 + ((ww<7)?0:((jw1<4)?1:2));
      bool v0ok = (j0 < LL), v1ok = (j1 < LL);

      float s0[4], s1[4], mt[4];
      #pragma unroll
      for (int r=0;r<4;r++){
        int i0 = basei[r] - cj0; if (i0 < 0) i0 = 0;
        int i1 = basei[r] - cj1; if (i1 < 0) i1 = 0;
        float b0 = rpbp[i0*NHEAD + head];
        float b1 = rpbp[i1*NHEAD + head];
        float t0 = fmaf(c0[r], QKSCALE, b0);
        float t1 = fmaf(c1[r], QKSCALE, b1);
        if (shifted){
          if (regj0 != regi[r]) t0 -= 100.f;
          if (regj1 != regi[r]) t1 -= 100.f;
        }
        s0[r] = v0ok ? t0 : -1e30f;
        s1[r] = v1ok ? t1 : -1e30f;
        mt[r] = fmaxf(s0[r], s1[r]);
      }
      #pragma unroll
      for (int o=1;o<16;o<<=1){
        #pragma unroll
        for (int r=0;r<4;r++) mt[r] = fmaxf(mt[r], __shfl_xor(mt[r], o));
      }
      float p0[4], p1[4], rs[4];
      #pragma unroll
      for (int r=0;r<4;r++){
        float mn = fmaxf(m_r[r], mt[r]);
        float al = __expf(m_r[r] - mn);
        m_r[r] = mn;
        p0[r] = __expf(s0[r] - mn);
        p1[r] = __expf(s1[r] - mn);
        l_r[r] *= al;
        oc0[r] *= al; oc1[r] *= al;
        rs[r] = p0[r] + p1[r];
      }
      #pragma unroll
      for (int o=1;o<16;o<<=1){
        #pragma unroll
        for (int r=0;r<4;r++) rs[r] += __shfl_xor(rs[r], o);
      }
      #pragma unroll
      for (int r=0;r<4;r++){
        l_r[r] += rs[r];
        lds[pbase + (quad*4+r)*32 + l15]      = f2b(p0[r]);
        lds[pbase + (quad*4+r)*32 + 16 + l15] = f2b(p1[r]);
      }
      // P (A-layout) and V^T (B-layout) frags
      short8 pa  = *reinterpret_cast<const short8*>(&lds[pbase + l15*32 + quad*8]);
      short8 vb0 = *reinterpret_cast<const short8*>(&lds[VOFF + l15*VSTRIDE + kbase + quad*8]);
      short8 vb1 = *reinterpret_cast<const short8*>(&lds[VOFF + (16+l15)*VSTRIDE + kbase + quad*8]);
      oc0 = __builtin_amdgcn_mfma_f32_16x16x32_bf16(pa, vb0, oc0, 0,0,0);
      oc1 = __builtin_amdgcn_mfma_f32_16x16x32_bf16(pa, vb1, oc1, 0,0,0);
    }

    #pragma unroll
    for (int r=0;r<4;r++){
      int i = qt*16 + quad*4 + r;
      if (i < LL){
        float inv = 1.f / l_r[r];
        long o = ((long)(w*LL + i))*CC + head*HDIM;
        out[o + l15]      = f2b(oc0[r]*inv);
        out[o + 16 + l15] = f2b(oc1[r]*inv);
      }
    }
  }
}

extern "C" void kernel_launch(void* const* d_in, const int* in_sizes, int n_in,
                              void* d_out, int out_size, void* d_ws, size_t ws_size,
                              hipStream_t stream)
{
  const float* x     = (const float*)d_in[0];
  const float* ln1g  = (const float*)d_in[1];
  const float* ln1b  = (const float*)d_in[2];
  const float* qkvw  = (const float*)d_in[3];
  const float* qkvb  = (const float*)d_in[4];
  const float* rpb   = (const float*)d_in[5];
  const float* projw = (const float*)d_in[6];
  const float* projb = (const float*)d_in[7];
  const float* ln2g  = (const float*)d_in[8];
  const float* ln2b  = (const float*)d_in[9];
  const float* fc1w  = (const float*)d_in[10];
  const float* fc1b  = (const float*)d_in[11];
  const float* fc2w  = (const float*)d_in[12];
  const float* fc2b  = (const float*)d_in[13];
  float* outf = (float*)d_out;           // residual stream lives here (f32)

  u16* buf1 = (u16*)d_ws;                               // bf16 activations, NTOK*128
  u16* bufq = buf1 + (size_t)NTOK*CC;                   // bf16 qkv chunk / mlp hidden

  for (int blk = 0; blk < 2; ++blk){
    const int sh = blk;
    const float* resid = (blk==0) ? x : outf;
    // LN1 + roll + window-partition gather (reads f32 resid)
    ln_kernel<<<NTOK/4, 256, 0, stream>>>(resid,
        ln1g + blk*CC, ln1b + blk*CC, buf1, 1, sh);
    // QKV + attention in 2 window-chunks of 64
    for (int c = 0; c < 2; ++c){
      gemm_rw_kernel<128,384,0><<<dim3(CROWS/64, 6), 256, 0, stream>>>(
          buf1 + (size_t)c*CROWS*CC, qkvw + (size_t)blk*128*384, 384,
          qkvb + blk*384, bufq);
      attn_kernel<<<WCHUNK*NHEAD, 256, 0, stream>>>(
          bufq, rpb + (size_t)blk*2535*NHEAD, buf1, sh, c*WCHUNK);
    }
    // proj + reverse/roll-back scatter + residual -> d_out (f32)
    gemm_proj_kernel<<<dim3(NTOK/64, 2), 256, 0, stream>>>(
        buf1, projw + (size_t)blk*128*128, projb + blk*CC, resid, outf, sh);
    // LN2 (reads d_out)
    ln_kernel<<<NTOK/4, 256, 0, stream>>>(outf,
        ln2g + blk*CC, ln2b + blk*CC, buf1, 0, 0);
    // MLP in 4 column-quarters of 128; hidden quarter reuses bufq region
    for (int q = 0; q < 4; ++q){
      gemm_rw_kernel<128,128,1><<<dim3(NTOK/64, 2), 256, 0, stream>>>(
          buf1, fc1w + (size_t)blk*128*512 + q*128, 512,
          fc1b + blk*512 + q*128, bufq);
      gemm_fc2q_kernel<<<dim3(NTOK/64, 2), 256, 0, stream>>>(
          bufq, fc2w + (size_t)blk*512*128 + (size_t)q*128*128,
          fc2b + blk*CC, outf, q==0 ? 1 : 0);
    }
  }
}

// Round 5
// 657.621 us; speedup vs baseline: 3.9529x; 2.4051x over previous
//
#include <hip/hip_runtime.h>
#include <hip/hip_bf16.h>
#include <math.h>

// VideoSwinBasicLayer: 2 swin blocks (W-MSA, SW-MSA) on (1,16,56,56,128), NH=4,
// window (8,7,7) -> L=392, nW=128, shift (4,3,3), HID=512. IO f32.
// R5: all GEMMs -> MFMA bf16 (128x128 tile); attn un-chunked (512 blocks, 2/CU)
// with precomputed bias matrix (pad=-1e30 absorbs j-bounds) and pre-scaled Q.
// ws: buf1 12.85MB | bufq 38.5MB | wtsT bf16 0.79MB | BiasF 2.6MB = 54.8MB.

#define NTOK 50176   // 16*56*56
#define CC   128
#define LL   392
#define NWIN 128
#define NHEAD 4
#define HDIM 32
#define QKSCALE 0.17677669529663687f  // 32^-0.5

// attention LDS layout (u16 units)
#define KSTRIDE 40
#define KOFF    0             // K: 416 x KSTRIDE  = 16640 u16
#define VSTRIDE 424
#define VOFF    16640         // V_T: 32 x VSTRIDE = 13568 u16
#define POFF    30208         // P: 4 waves x 512  = 2048 u16
#define LDS_U16 32256         // 64512 B

typedef unsigned short u16;
typedef unsigned int   u32;
typedef __attribute__((ext_vector_type(8))) short short8;
typedef __attribute__((ext_vector_type(4))) float f32x4;

__device__ __forceinline__ u16 f2b(float f){
  __hip_bfloat16 h = __float2bfloat16(f);
  return *reinterpret_cast<u16*>(&h);
}

// window-ordered row r -> flat token position (roll(+shift) both directions).
__device__ __forceinline__ int row_to_pos(int r, int shifted){
  int w = r / LL, t = r - w*LL;
  int wd = w >> 6, wh = (w >> 3) & 7, ww = w & 7;
  int td = t / 49, rem = t - td*49, th = rem / 7, tw = rem - th*7;
  int d = wd*8 + td, h = wh*7 + th, x = ww*7 + tw;
  if (shifted){ d = (d+4)&15; h += 3; if (h>=56) h-=56; x += 3; if (x>=56) x-=56; }
  return (d*56 + h)*56 + x;
}

// LayerNorm over C=128 (f32 src), bf16 out. One wave per row.
__global__ __launch_bounds__(256) void ln_kernel(
    const float* __restrict__ xf, const float* __restrict__ g,
    const float* __restrict__ b, u16* __restrict__ out, int do_map, int shifted)
{
  int wave = threadIdx.x >> 6, lane = threadIdx.x & 63;
  int r = blockIdx.x*4 + wave;
  int pos = do_map ? row_to_pos(r, shifted) : r;
  long src = (long)pos * CC;
  float v0 = xf[src+lane], v1 = xf[src+64+lane];
  float s = v0+v1, ss = v0*v0 + v1*v1;
  #pragma unroll
  for (int o=32; o>0; o>>=1){ s += __shfl_xor(s,o); ss += __shfl_xor(ss,o); }
  float mean = s*(1.f/CC);
  float var  = ss*(1.f/CC) - mean*mean;
  float rstd = rsqrtf(var + 1e-5f);
  long dst = (long)r*CC;
  out[dst + lane]      = f2b((v0-mean)*rstd*g[lane]    + b[lane]);
  out[dst + 64 + lane] = f2b((v1-mean)*rstd*g[64+lane] + b[64+lane]);
}

// Transpose+convert weights: in f32 [Kd][Nd] row-major -> out bf16 [Nd][Kd].
__global__ __launch_bounds__(256) void wt_kernel(
    const float* __restrict__ in, u16* __restrict__ out, int Kd, int Nd, int total)
{
  int t = blockIdx.x*256 + threadIdx.x;
  if (t >= total) return;
  int n = t / Kd, k = t - n*Kd;
  out[t] = f2b(in[k*Nd + n]);
}

// Precompute attention bias BiasF[h][i][j] (j padded to 416; pad = -1e30,
// doubling as the j>=392 validity mask).
__global__ __launch_bounds__(256) void biasf_kernel(
    const float* __restrict__ rpb, float* __restrict__ biasf)
{
  int t = blockIdx.x*256 + threadIdx.x;
  if (t >= NHEAD*LL*416) return;
  int j = t % 416; int rest = t / 416; int i = rest % LL; int h = rest / LL;
  float v = -1e30f;
  if (j < LL){
    int td=i/49, rm=i-td*49, th=rm/7, tw=rm-th*7;
    int jd=j/49, jr=j-jd*49, jh=jr/7, jw=jr-jh*7;
    int idx = (td-jd)*169 + (th-jh)*13 + (tw-jw) + 1267;
    v = rpb[idx*NHEAD + h];
  }
  biasf[t] = v;
}

// MFMA GEMM: C[128x128 tile] = A[rows x KD](bf16) @ Wt^T, Wt stored [N][K] bf16
// (n-major, row stride ldw). 256 thr = 4 waves, each 64x64 via 4x4 mfma grid.
// EPI: 0 = (+bias)*scale -> bf16 (qkv; scale only on blockIdx.y==0)
//      1 = +bias, GELU -> bf16 (fc1 half)
//      2 = +bias, scatter row_to_pos, +Res -> f32 (proj)
//      3 = accumulate into OutF (+bias if use_bias) (fc2 half)
template<int KD, int EPI>
__global__ __launch_bounds__(256) void mm_kernel(
    const u16* __restrict__ A, const u16* __restrict__ Wt, int ldw,
    const float* __restrict__ bias, u16* __restrict__ OutB, int ldo,
    float* __restrict__ OutF, const float* __restrict__ Res,
    float scaleq, int shifted, int use_bias)
{
  __shared__ u16 As[128*40];
  __shared__ u16 Bs[128*40];
  const int tid = threadIdx.x, lane = tid & 63, wv = tid >> 6;
  const int quad = lane >> 4, l15 = lane & 15;
  const int rh = wv >> 1, ch = wv & 1;
  const int r0 = blockIdx.x * 128, n0 = blockIdx.y * 128;

  f32x4 acc[4][4] = {};

  for (int kt = 0; kt < KD/32; kt++){
    const int k0 = kt*32;
    #pragma unroll
    for (int t=0;t<2;t++){
      int L = t*256 + tid;            // 0..511
      int row = L >> 2, part = L & 3; // 128 rows x 4x8-elem parts
      short8 av = *reinterpret_cast<const short8*>(&A[(long)(r0+row)*KD + k0 + part*8]);
      short8 bv = *reinterpret_cast<const short8*>(&Wt[(long)(n0+row)*ldw + k0 + part*8]);
      *reinterpret_cast<short8*>(&As[row*40 + part*8]) = av;
      *reinterpret_cast<short8*>(&Bs[row*40 + part*8]) = bv;
    }
    __syncthreads();
    short8 af[4], bf[4];
    #pragma unroll
    for (int rt=0;rt<4;rt++)
      af[rt] = *reinterpret_cast<const short8*>(&As[(rh*64 + rt*16 + l15)*40 + quad*8]);
    #pragma unroll
    for (int ct=0;ct<4;ct++)
      bf[ct] = *reinterpret_cast<const short8*>(&Bs[(ch*64 + ct*16 + l15)*40 + quad*8]);
    #pragma unroll
    for (int rt=0;rt<4;rt++)
      #pragma unroll
      for (int ct=0;ct<4;ct++)
        acc[rt][ct] = __builtin_amdgcn_mfma_f32_16x16x32_bf16(af[rt], bf[ct], acc[rt][ct], 0,0,0);
    __syncthreads();
  }

  #pragma unroll
  for (int rt=0;rt<4;rt++){
    #pragma unroll
    for (int rr=0;rr<4;rr++){
      const int row_g = r0 + rh*64 + rt*16 + quad*4 + rr;
      long pos = 0;
      if (EPI == 2) pos = (long)row_to_pos(row_g, shifted) * CC;
      #pragma unroll
      for (int ct=0;ct<4;ct++){
        const int col_l = ch*64 + ct*16 + l15;
        const int col_g = n0 + col_l;
        float v = acc[rt][ct][rr];
        if (EPI == 0){
          float sc = (blockIdx.y == 0) ? scaleq : 1.f;
          v = (v + bias[col_g]) * sc;
          OutB[(long)row_g*ldo + col_g] = f2b(v);
        } else if (EPI == 1){
          v += bias[col_g];
          v = 0.5f*v*(1.f + erff(v*0.70710678118654752f));
          OutB[(long)row_g*ldo + col_g] = f2b(v);
        } else if (EPI == 2){
          OutF[pos + col_g] = Res[pos + col_g] + v + bias[col_g];
        } else {
          float o = OutF[(long)row_g*CC + col_g] + v;
          if (use_bias) o += bias[col_g];
          OutF[(long)row_g*CC + col_g] = o;
        }
      }
    }
  }
}

// MFMA flash attention. One block per (window, head); 4 waves x 16-row q-tiles.
// Bias (incl. j-pad mask) from precomputed BiasF; Q pre-scaled in qkv epilogue.
__global__ __launch_bounds__(256) void attn_kernel(
    const u16* __restrict__ qkv, const float* __restrict__ biasf,
    u16* __restrict__ out, int shifted)
{
  __shared__ __align__(16) u16 lds[LDS_U16];

  const int w = blockIdx.x >> 2, head = blockIdx.x & 3;
  const int tid = threadIdx.x, lane = tid & 63, wave = tid >> 6;
  const int quad = lane >> 4, l15 = lane & 15;
  const long qkvbase = (long)w * LL * 384;
  const int wd = w>>6, wh = (w>>3)&7, ww = w&7;
  const int pbase = POFF + wave*512;
  const float* __restrict__ bh = &biasf[(long)head*LL*416];

  // stage K (rows 392..415 zeroed)
  for (int idx = tid; idx < 416*4; idx += 256){
    int key = idx >> 2, part = idx & 3;
    short8 val = {0,0,0,0,0,0,0,0};
    if (key < LL)
      val = *reinterpret_cast<const short8*>(&qkv[qkvbase + (long)key*384 + 128 + head*HDIM + part*8]);
    *reinterpret_cast<short8*>(&lds[KOFF + key*KSTRIDE + part*8]) = val;
  }
  // stage V transposed (keys 392..415 zeroed)
  for (int idx = tid; idx < 416*32; idx += 256){
    int key = idx >> 5, d = idx & 31;
    u16 v = (key < LL) ? qkv[qkvbase + (long)key*384 + 256 + head*HDIM + d] : (u16)0;
    lds[VOFF + d*VSTRIDE + key] = v;
  }
  __syncthreads();

  for (int qt = wave; qt < 25; qt += 4){
    int qrow = qt*16 + l15; if (qrow > LL-1) qrow = LL-1;
    short8 qf = *reinterpret_cast<const short8*>(&qkv[qkvbase + (long)qrow*384 + head*HDIM + quad*8]);

    float m_r[4], l_r[4];
    int i_r[4], regi[4];
    #pragma unroll
    for (int r=0;r<4;r++){
      int i = qt*16 + quad*4 + r; if (i > LL-1) i = LL-1;
      i_r[r] = i;
      int td = i/49, rm = i - td*49, th = rm/7, tw = rm - th*7;
      int dr = (wd==0)?0:((td<4)?1:2);
      int hr = (wh<7)?0:((th<4)?1:2);
      int wr = (ww<7)?0:((tw<4)?1:2);
      regi[r] = dr*9 + hr*3 + wr;
      m_r[r] = -1e30f; l_r[r] = 0.f;
    }
    f32x4 oc0 = {0.f,0.f,0.f,0.f}, oc1 = {0.f,0.f,0.f,0.f};

    for (int s = 0; s < 13; s++){
      const int kbase = s*32;
      const int j0 = kbase + l15, j1 = j0 + 16;
      // bias loads early (L2-hot, coalesced) to overlap with mfma
      float b0[4], b1[4];
      #pragma unroll
      for (int r=0;r<4;r++){
        const float* bp = &bh[(long)i_r[r]*416];
        b0[r] = bp[j0]; b1[r] = bp[j1];
      }
      short8 kf0 = *reinterpret_cast<const short8*>(&lds[KOFF + j0*KSTRIDE + quad*8]);
      short8 kf1 = *reinterpret_cast<const short8*>(&lds[KOFF + j1*KSTRIDE + quad*8]);
      f32x4 z = {0.f,0.f,0.f,0.f};
      f32x4 c0 = __builtin_amdgcn_mfma_f32_16x16x32_bf16(qf, kf0, z, 0,0,0);
      f32x4 c1 = __builtin_amdgcn_mfma_f32_16x16x32_bf16(qf, kf1, z, 0,0,0);

      // key region classes for shifted mask
      int jd0 = j0/49, jr0 = j0 - jd0*49, jh0 = jr0/7, jw0 = jr0 - jh0*7;
      int jd1 = j1/49, jr1 = j1 - jd1*49, jh1 = jr1/7, jw1 = jr1 - jh1*7;
      int regj0 = ((wd==0)?0:((jd0<4)?1:2))*9 + ((wh<7)?0:((jh0<4)?1:2))*3 + ((ww<7)?0:((jw0<4)?1:2));
      int regj1 = ((wd==0)?0:((jd1<4)?1:2))*9 + ((wh<7)?0:((jh1<4)?1:2))*3 + ((ww<7)?0:((jw1<4)?1:2));

      float s0[4], s1[4], mt[4];
      #pragma unroll
      for (int r=0;r<4;r++){
        float t0 = c0[r] + b0[r];
        float t1 = c1[r] + b1[r];
        if (shifted){
          if (regj0 != regi[r]) t0 -= 100.f;
          if (regj1 != regi[r]) t1 -= 100.f;
        }
        s0[r] = t0; s1[r] = t1;
        mt[r] = fmaxf(t0, t1);
      }
      #pragma unroll
      for (int o=1;o<16;o<<=1){
        #pragma unroll
        for (int r=0;r<4;r++) mt[r] = fmaxf(mt[r], __shfl_xor(mt[r], o));
      }
      float p0[4], p1[4], rs[4];
      #pragma unroll
      for (int r=0;r<4;r++){
        float mn = fmaxf(m_r[r], mt[r]);
        float al = __expf(m_r[r] - mn);
        m_r[r] = mn;
        p0[r] = __expf(s0[r] - mn);
        p1[r] = __expf(s1[r] - mn);
        l_r[r] *= al;
        oc0[r] *= al; oc1[r] *= al;
        rs[r] = p0[r] + p1[r];
      }
      #pragma unroll
      for (int o=1;o<16;o<<=1){
        #pragma unroll
        for (int r=0;r<4;r++) rs[r] += __shfl_xor(rs[r], o);
      }
      #pragma unroll
      for (int r=0;r<4;r++){
        l_r[r] += rs[r];
        lds[pbase + (quad*4+r)*32 + l15]      = f2b(p0[r]);
        lds[pbase + (quad*4+r)*32 + 16 + l15] = f2b(p1[r]);
      }
      short8 pa  = *reinterpret_cast<const short8*>(&lds[pbase + l15*32 + quad*8]);
      short8 vb0 = *reinterpret_cast<const short8*>(&lds[VOFF + l15*VSTRIDE + kbase + quad*8]);
      short8 vb1 = *reinterpret_cast<const short8*>(&lds[VOFF + (16+l15)*VSTRIDE + kbase + quad*8]);
      oc0 = __builtin_amdgcn_mfma_f32_16x16x32_bf16(pa, vb0, oc0, 0,0,0);
      oc1 = __builtin_amdgcn_mfma_f32_16x16x32_bf16(pa, vb1, oc1, 0,0,0);
    }

    #pragma unroll
    for (int r=0;r<4;r++){
      int i = qt*16 + quad*4 + r;
      if (i < LL){
        float inv = 1.f / l_r[r];
        long o = ((long)(w*LL + i))*CC + head*HDIM;
        out[o + l15]      = f2b(oc0[r]*inv);
        out[o + 16 + l15] = f2b(oc1[r]*inv);
      }
    }
  }
}

extern "C" void kernel_launch(void* const* d_in, const int* in_sizes, int n_in,
                              void* d_out, int out_size, void* d_ws, size_t ws_size,
                              hipStream_t stream)
{
  const float* x     = (const float*)d_in[0];
  const float* ln1g  = (const float*)d_in[1];
  const float* ln1b  = (const float*)d_in[2];
  const float* qkvw  = (const float*)d_in[3];
  const float* qkvb  = (const float*)d_in[4];
  const float* rpb   = (const float*)d_in[5];
  const float* projw = (const float*)d_in[6];
  const float* projb = (const float*)d_in[7];
  const float* ln2g  = (const float*)d_in[8];
  const float* ln2b  = (const float*)d_in[9];
  const float* fc1w  = (const float*)d_in[10];
  const float* fc1b  = (const float*)d_in[11];
  const float* fc2w  = (const float*)d_in[12];
  const float* fc2b  = (const float*)d_in[13];
  float* outf = (float*)d_out;                  // f32 residual stream / output

  u16*   buf1  = (u16*)d_ws;                    // bf16 act, NTOK*128
  u16*   bufq  = buf1 + (size_t)NTOK*CC;        // bf16 qkv full / mlp hidden half
  u16*   wts   = bufq + (size_t)NTOK*384;       // transposed bf16 weights
  float* biasf = (float*)(wts + 393216);        // BiasF[4][392][416]

  // transposed bf16 weights (both blocks)
  for (int blk = 0; blk < 2; ++blk){
    u16* wb = wts + (size_t)blk*196608;
    wt_kernel<<<(49152+255)/256, 256, 0, stream>>>(qkvw + (size_t)blk*128*384, wb,          128, 384, 49152);
    wt_kernel<<<(16384+255)/256, 256, 0, stream>>>(projw + (size_t)blk*128*128, wb+49152,   128, 128, 16384);
    wt_kernel<<<(65536+255)/256, 256, 0, stream>>>(fc1w  + (size_t)blk*128*512, wb+65536,   128, 512, 65536);
    wt_kernel<<<(65536+255)/256, 256, 0, stream>>>(fc2w  + (size_t)blk*512*128, wb+131072,  512, 128, 65536);
  }

  for (int blk = 0; blk < 2; ++blk){
    const int sh = blk;
    const float* resid = (blk==0) ? x : outf;
    u16* wb = wts + (size_t)blk*196608;

    biasf_kernel<<<(NHEAD*LL*416+255)/256, 256, 0, stream>>>(
        rpb + (size_t)blk*2535*NHEAD, biasf);
    // LN1 + roll + window-partition gather
    ln_kernel<<<NTOK/4, 256, 0, stream>>>(resid,
        ln1g + blk*CC, ln1b + blk*CC, buf1, 1, sh);
    // QKV GEMM (q pre-scaled)
    mm_kernel<128,0><<<dim3(392,3), 256, 0, stream>>>(
        buf1, wb, 128, qkvb + blk*384, bufq, 384,
        nullptr, nullptr, QKSCALE, 0, 0);
    // attention (all 128 windows x 4 heads)
    attn_kernel<<<NWIN*NHEAD, 256, 0, stream>>>(bufq, biasf, buf1, sh);
    // proj + reverse/roll-back scatter + residual -> outf
    mm_kernel<128,2><<<dim3(392,1), 256, 0, stream>>>(
        buf1, wb+49152, 128, projb + blk*CC, nullptr, 0,
        outf, resid, 1.f, sh, 0);
    // LN2
    ln_kernel<<<NTOK/4, 256, 0, stream>>>(outf,
        ln2g + blk*CC, ln2b + blk*CC, buf1, 0, 0);
    // MLP in 2 column-halves of 256 (hidden half reuses bufq)
    for (int h = 0; h < 2; ++h){
      mm_kernel<128,1><<<dim3(392,2), 256, 0, stream>>>(
          buf1, wb + 65536 + (size_t)h*256*128, 128,
          fc1b + blk*512 + h*256, bufq, 256,
          nullptr, nullptr, 1.f, 0, 0);
      mm_kernel<256,3><<<dim3(392,1), 256, 0, stream>>>(
          bufq, wb + 131072 + h*256, 512,
          fc2b + blk*CC, nullptr, 0,
          outf, nullptr, 1.f, 0, h==0 ? 1 : 0);
    }
  }
}

// Round 6
// 604.454 us; speedup vs baseline: 4.3006x; 1.0880x over previous
//
#include <hip/hip_runtime.h>
#include <hip/hip_bf16.h>
#include <math.h>

// VideoSwinBasicLayer: 2 swin blocks (W-MSA, SW-MSA) on (1,16,56,56,128), NH=4,
// window (8,7,7) -> L=392, nW=128, shift (4,3,3), HID=512. IO f32.
// R6: attention in S^T orientation -> per-lane scalar softmax state (2 shfl
// reductions), packed bf16 bias(+shift-mask) table (8 window classes), P via
// 2x ds_write_b64 + 1x ds_read_b128. GEMMs unchanged (MFMA 128x128 tile).
// ws: buf1 12.85MB | bufq 38.5MB | wtsT 0.79MB | bm 10.44MB = 62.6MB.

#define NTOK 50176   // 16*56*56
#define CC   128
#define LL   392
#define NWIN 128
#define NHEAD 4
#define HDIM 32
#define QKSCALE 0.17677669529663687f  // 32^-0.5

// attention LDS layout (u16 units)
#define KSTRIDE 40
#define KOFF    0             // K: 416 x KSTRIDE  = 16640 u16
#define VSTRIDE 424
#define VOFF    16640         // V_T: 32 x VSTRIDE = 13568 u16
#define POFF    30208         // P: 4 waves x 512  = 2048 u16
#define LDS_U16 32256         // 64512 B

#define BM_PER_HEAD (13*16*392)            // u32 per (cls,head) slice
#define BM_TOTAL    (8*4*BM_PER_HEAD)      // 2,609,152 u32 = 10.44 MB

typedef unsigned short u16;
typedef unsigned int   u32;
typedef unsigned long long u64;
typedef __attribute__((ext_vector_type(8))) short short8;
typedef __attribute__((ext_vector_type(4))) float f32x4;

__device__ __forceinline__ float b2f_lo(u32 u){ return __uint_as_float(u<<16); }
__device__ __forceinline__ float b2f_hi(u32 u){ return __uint_as_float(u & 0xffff0000u); }
__device__ __forceinline__ u16 f2b(float f){
  __hip_bfloat16 h = __float2bfloat16(f);
  return *reinterpret_cast<u16*>(&h);
}

// window-ordered row r -> flat token position (roll(+shift) both directions).
__device__ __forceinline__ int row_to_pos(int r, int shifted){
  int w = r / LL, t = r - w*LL;
  int wd = w >> 6, wh = (w >> 3) & 7, ww = w & 7;
  int td = t / 49, rem = t - td*49, th = rem / 7, tw = rem - th*7;
  int d = wd*8 + td, h = wh*7 + th, x = ww*7 + tw;
  if (shifted){ d = (d+4)&15; h += 3; if (h>=56) h-=56; x += 3; if (x>=56) x-=56; }
  return (d*56 + h)*56 + x;
}

// LayerNorm over C=128 (f32 src), bf16 out. One wave per row.
__global__ __launch_bounds__(256) void ln_kernel(
    const float* __restrict__ xf, const float* __restrict__ g,
    const float* __restrict__ b, u16* __restrict__ out, int do_map, int shifted)
{
  int wave = threadIdx.x >> 6, lane = threadIdx.x & 63;
  int r = blockIdx.x*4 + wave;
  int pos = do_map ? row_to_pos(r, shifted) : r;
  long src = (long)pos * CC;
  float v0 = xf[src+lane], v1 = xf[src+64+lane];
  float s = v0+v1, ss = v0*v0 + v1*v1;
  #pragma unroll
  for (int o=32; o>0; o>>=1){ s += __shfl_xor(s,o); ss += __shfl_xor(ss,o); }
  float mean = s*(1.f/CC);
  float var  = ss*(1.f/CC) - mean*mean;
  float rstd = rsqrtf(var + 1e-5f);
  long dst = (long)r*CC;
  out[dst + lane]      = f2b((v0-mean)*rstd*g[lane]    + b[lane]);
  out[dst + 64 + lane] = f2b((v1-mean)*rstd*g[64+lane] + b[64+lane]);
}

// Transpose+convert weights: in f32 [Kd][Nd] row-major -> out bf16 [Nd][Kd].
__global__ __launch_bounds__(256) void wt_kernel(
    const float* __restrict__ in, u16* __restrict__ out, int Kd, int Nd, int total)
{
  int t = blockIdx.x*256 + threadIdx.x;
  if (t >= total) return;
  int n = t / Kd, k = t - n*Kd;
  out[t] = f2b(in[k*Nd + n]);
}

// Packed bias(+mask) table: bm[cls][h][s][jj][i] u32 = (bf16 v(j=s*32+jj, i),
// bf16 v(j+16, i)).  v = rpb-bias - 100*maskneq(cls);  j>=392 -> -1e30.
__global__ __launch_bounds__(256) void biasm_kernel(
    const float* __restrict__ rpb, u32* __restrict__ bm)
{
  int t = blockIdx.x*256 + threadIdx.x;
  if (t >= BM_TOTAL) return;
  int i = t % 392; int rest = t / 392;
  int jj = rest % 16; rest /= 16;
  int s  = rest % 13; rest /= 13;
  int h  = rest % 4;  int cls = rest / 4;
  int tdi=i/49, rmi=i-tdi*49, thi=rmi/7, twi=rmi-thi*7;
  u32 pack = 0;
  #pragma unroll
  for (int half=0; half<2; half++){
    int j = s*32 + jj + half*16;
    float v = -1e30f;
    if (j < LL){
      int tdj=j/49, rmj=j-tdj*49, thj=rmj/7, twj=rmj-thj*7;
      int idx = (tdi-tdj)*169 + (thi-thj)*13 + (twi-twj) + 1267;
      v = rpb[idx*NHEAD + h];
      bool neq = ((cls&4) && ((tdi<4) != (tdj<4)))
              || ((cls&2) && ((thi<4) != (thj<4)))
              || ((cls&1) && ((twi<4) != (twj<4)));
      if (neq) v -= 100.f;
    }
    pack |= ((u32)f2b(v)) << (16*half);
  }
  bm[t] = pack;
}

// MFMA GEMM: C[128x128 tile] = A[rows x KD](bf16) @ Wt^T, Wt stored [N][K] bf16.
// EPI: 0 = (+bias)*scale -> bf16 (qkv; scale only blockIdx.y==0)
//      1 = +bias, GELU -> bf16 | 2 = +bias, scatter, +Res -> f32 | 3 = accum f32
template<int KD, int EPI>
__global__ __launch_bounds__(256) void mm_kernel(
    const u16* __restrict__ A, const u16* __restrict__ Wt, int ldw,
    const float* __restrict__ bias, u16* __restrict__ OutB, int ldo,
    float* __restrict__ OutF, const float* __restrict__ Res,
    float scaleq, int shifted, int use_bias)
{
  __shared__ u16 As[128*40];
  __shared__ u16 Bs[128*40];
  const int tid = threadIdx.x, lane = tid & 63, wv = tid >> 6;
  const int quad = lane >> 4, l15 = lane & 15;
  const int rh = wv >> 1, ch = wv & 1;
  const int r0 = blockIdx.x * 128, n0 = blockIdx.y * 128;

  f32x4 acc[4][4] = {};

  for (int kt = 0; kt < KD/32; kt++){
    const int k0 = kt*32;
    #pragma unroll
    for (int t=0;t<2;t++){
      int L = t*256 + tid;
      int row = L >> 2, part = L & 3;
      short8 av = *reinterpret_cast<const short8*>(&A[(long)(r0+row)*KD + k0 + part*8]);
      short8 bv = *reinterpret_cast<const short8*>(&Wt[(long)(n0+row)*ldw + k0 + part*8]);
      *reinterpret_cast<short8*>(&As[row*40 + part*8]) = av;
      *reinterpret_cast<short8*>(&Bs[row*40 + part*8]) = bv;
    }
    __syncthreads();
    short8 af[4], bf[4];
    #pragma unroll
    for (int rt=0;rt<4;rt++)
      af[rt] = *reinterpret_cast<const short8*>(&As[(rh*64 + rt*16 + l15)*40 + quad*8]);
    #pragma unroll
    for (int ct=0;ct<4;ct++)
      bf[ct] = *reinterpret_cast<const short8*>(&Bs[(ch*64 + ct*16 + l15)*40 + quad*8]);
    #pragma unroll
    for (int rt=0;rt<4;rt++)
      #pragma unroll
      for (int ct=0;ct<4;ct++)
        acc[rt][ct] = __builtin_amdgcn_mfma_f32_16x16x32_bf16(af[rt], bf[ct], acc[rt][ct], 0,0,0);
    __syncthreads();
  }

  #pragma unroll
  for (int rt=0;rt<4;rt++){
    #pragma unroll
    for (int rr=0;rr<4;rr++){
      const int row_g = r0 + rh*64 + rt*16 + quad*4 + rr;
      long pos = 0;
      if (EPI == 2) pos = (long)row_to_pos(row_g, shifted) * CC;
      #pragma unroll
      for (int ct=0;ct<4;ct++){
        const int col_g = n0 + ch*64 + ct*16 + l15;
        float v = acc[rt][ct][rr];
        if (EPI == 0){
          float sc = (blockIdx.y == 0) ? scaleq : 1.f;
          v = (v + bias[col_g]) * sc;
          OutB[(long)row_g*ldo + col_g] = f2b(v);
        } else if (EPI == 1){
          v += bias[col_g];
          v = 0.5f*v*(1.f + erff(v*0.70710678118654752f));
          OutB[(long)row_g*ldo + col_g] = f2b(v);
        } else if (EPI == 2){
          OutF[pos + col_g] = Res[pos + col_g] + v + bias[col_g];
        } else {
          float o = OutF[(long)row_g*CC + col_g] + v;
          if (use_bias) o += bias[col_g];
          OutF[(long)row_g*CC + col_g] = o;
        }
      }
    }
  }
}

// MFMA flash attention, S^T orientation. One block per (window, head); 4 waves
// x 16-row q-tiles. S^T = mfma(K,Q) puts q-row = lane&15 -> scalar softmax
// state, 2-shfl reductions. Bias+mask from packed bm table. PV = mfma(P, V^T)
// with P via wave-private LDS (2x b64 write, 1x b128 read).
__global__ __launch_bounds__(256) void attn_kernel(
    const u16* __restrict__ qkv, const u32* __restrict__ bm,
    u16* __restrict__ out, int shifted)
{
  __shared__ __align__(16) u16 lds[LDS_U16];

  const int w = blockIdx.x >> 2, head = blockIdx.x & 3;
  const int tid = threadIdx.x, lane = tid & 63, wave = tid >> 6;
  const int quad = lane >> 4, l15 = lane & 15;
  const long qkvbase = (long)w * LL * 384;
  const int wd = w>>6, wh = (w>>3)&7, ww = w&7;
  const int cls = shifted ? (((wd!=0)?4:0) | ((wh==7)?2:0) | ((ww==7)?1:0)) : 0;
  const u32* __restrict__ bmh = bm + (size_t)(cls*NHEAD + head)*BM_PER_HEAD;
  const int pbase = POFF + wave*512;

  // stage K (rows 392..415 zeroed)
  for (int idx = tid; idx < 416*4; idx += 256){
    int key = idx >> 2, part = idx & 3;
    short8 val = {0,0,0,0,0,0,0,0};
    if (key < LL)
      val = *reinterpret_cast<const short8*>(&qkv[qkvbase + (long)key*384 + 128 + head*HDIM + part*8]);
    *reinterpret_cast<short8*>(&lds[KOFF + key*KSTRIDE + part*8]) = val;
  }
  // stage V transposed (keys 392..415 zeroed)
  for (int idx = tid; idx < 416*32; idx += 256){
    int key = idx >> 5, d = idx & 31;
    u16 v = (key < LL) ? qkv[qkvbase + (long)key*384 + 256 + head*HDIM + d] : (u16)0;
    lds[VOFF + d*VSTRIDE + key] = v;
  }
  __syncthreads();

  for (int qt = wave; qt < 25; qt += 4){
    int iq = qt*16 + l15; if (iq > LL-1) iq = LL-1;
    // Q as B-frag: lane&15 = q-row, k = quad*8+j dims
    short8 qf = *reinterpret_cast<const short8*>(&qkv[qkvbase + (long)iq*384 + head*HDIM + quad*8]);

    float m_s = -1e30f, l_s = 0.f;
    f32x4 oc0 = {0.f,0.f,0.f,0.f}, oc1 = {0.f,0.f,0.f,0.f};

    for (int s = 0; s < 13; s++){
      const int kbase = s*32;
      // packed bias+mask (global, L2/L3-hot, coalesced over l15)
      u32 bmv[4];
      const u32* bp = &bmh[(size_t)(s*16)*392 + iq];
      #pragma unroll
      for (int r=0;r<4;r++) bmv[r] = bp[(quad*4+r)*392];

      short8 kf0 = *reinterpret_cast<const short8*>(&lds[KOFF + (kbase + l15)*KSTRIDE + quad*8]);
      short8 kf1 = *reinterpret_cast<const short8*>(&lds[KOFF + (kbase + 16 + l15)*KSTRIDE + quad*8]);
      f32x4 z = {0.f,0.f,0.f,0.f};
      f32x4 c0 = __builtin_amdgcn_mfma_f32_16x16x32_bf16(kf0, qf, z, 0,0,0);
      f32x4 c1 = __builtin_amdgcn_mfma_f32_16x16x32_bf16(kf1, qf, z, 0,0,0);
      // c0[r]: S[qrow=iq][key=kbase+quad*4+r]; c1[r]: key +16

      float s0[4], s1[4];
      float mt = -1e30f;
      #pragma unroll
      for (int r=0;r<4;r++){
        s0[r] = c0[r] + b2f_lo(bmv[r]);
        s1[r] = c1[r] + b2f_hi(bmv[r]);
        mt = fmaxf(mt, fmaxf(s0[r], s1[r]));
      }
      mt = fmaxf(mt, __shfl_xor(mt, 16));
      mt = fmaxf(mt, __shfl_xor(mt, 32));
      float mn = fmaxf(m_s, mt);
      float al = __expf(m_s - mn);
      m_s = mn;

      float rs = 0.f;
      u16 pb0[4], pb1[4];
      #pragma unroll
      for (int r=0;r<4;r++){
        float p0 = __expf(s0[r] - mn);
        float p1 = __expf(s1[r] - mn);
        rs += p0 + p1;
        pb0[r] = f2b(p0); pb1[r] = f2b(p1);
      }
      rs += __shfl_xor(rs, 16);
      rs += __shfl_xor(rs, 32);
      l_s = l_s*al + rs;

      // P -> wave-private LDS: row = q-row (l15), cols = key offsets
      u64 w0 = (u64)pb0[0] | ((u64)pb0[1]<<16) | ((u64)pb0[2]<<32) | ((u64)pb0[3]<<48);
      u64 w1 = (u64)pb1[0] | ((u64)pb1[1]<<16) | ((u64)pb1[2]<<32) | ((u64)pb1[3]<<48);
      *reinterpret_cast<u64*>(&lds[pbase + l15*32 + quad*4])      = w0;
      *reinterpret_cast<u64*>(&lds[pbase + l15*32 + 16 + quad*4]) = w1;

      // rescale O (C-layout rows = q-rows quad*4+r); alpha lives at lane quad*4+r
      #pragma unroll
      for (int r=0;r<4;r++){
        float alr = __shfl(al, quad*4 + r);
        oc0[r] *= alr; oc1[r] *= alr;
      }

      short8 pa  = *reinterpret_cast<const short8*>(&lds[pbase + l15*32 + quad*8]);
      short8 vb0 = *reinterpret_cast<const short8*>(&lds[VOFF + l15*VSTRIDE + kbase + quad*8]);
      short8 vb1 = *reinterpret_cast<const short8*>(&lds[VOFF + (16+l15)*VSTRIDE + kbase + quad*8]);
      oc0 = __builtin_amdgcn_mfma_f32_16x16x32_bf16(pa, vb0, oc0, 0,0,0);
      oc1 = __builtin_amdgcn_mfma_f32_16x16x32_bf16(pa, vb1, oc1, 0,0,0);
    }

    float inv = 1.f / l_s;
    #pragma unroll
    for (int r=0;r<4;r++){
      float invr = __shfl(inv, quad*4 + r);
      int i = qt*16 + quad*4 + r;
      if (i < LL){
        long o = ((long)(w*LL + i))*CC + head*HDIM;
        out[o + l15]      = f2b(oc0[r]*invr);
        out[o + 16 + l15] = f2b(oc1[r]*invr);
      }
    }
  }
}

extern "C" void kernel_launch(void* const* d_in, const int* in_sizes, int n_in,
                              void* d_out, int out_size, void* d_ws, size_t ws_size,
                              hipStream_t stream)
{
  const float* x     = (const float*)d_in[0];
  const float* ln1g  = (const float*)d_in[1];
  const float* ln1b  = (const float*)d_in[2];
  const float* qkvw  = (const float*)d_in[3];
  const float* qkvb  = (const float*)d_in[4];
  const float* rpb   = (const float*)d_in[5];
  const float* projw = (const float*)d_in[6];
  const float* projb = (const float*)d_in[7];
  const float* ln2g  = (const float*)d_in[8];
  const float* ln2b  = (const float*)d_in[9];
  const float* fc1w  = (const float*)d_in[10];
  const float* fc1b  = (const float*)d_in[11];
  const float* fc2w  = (const float*)d_in[12];
  const float* fc2b  = (const float*)d_in[13];
  float* outf = (float*)d_out;                  // f32 residual stream / output

  u16* buf1 = (u16*)d_ws;                       // bf16 act, NTOK*128
  u16* bufq = buf1 + (size_t)NTOK*CC;           // bf16 qkv / mlp hidden half
  u16* wts  = bufq + (size_t)NTOK*384;          // transposed bf16 weights
  u32* bm   = (u32*)(wts + 393216);             // packed bias+mask table

  for (int blk = 0; blk < 2; ++blk){
    u16* wb = wts + (size_t)blk*196608;
    wt_kernel<<<(49152+255)/256, 256, 0, stream>>>(qkvw + (size_t)blk*128*384, wb,          128, 384, 49152);
    wt_kernel<<<(16384+255)/256, 256, 0, stream>>>(projw + (size_t)blk*128*128, wb+49152,   128, 128, 16384);
    wt_kernel<<<(65536+255)/256, 256, 0, stream>>>(fc1w  + (size_t)blk*128*512, wb+65536,   128, 512, 65536);
    wt_kernel<<<(65536+255)/256, 256, 0, stream>>>(fc2w  + (size_t)blk*512*128, wb+131072,  512, 128, 65536);
  }

  for (int blk = 0; blk < 2; ++blk){
    const int sh = blk;
    const float* resid = (blk==0) ? x : outf;
    u16* wb = wts + (size_t)blk*196608;

    biasm_kernel<<<(BM_TOTAL+255)/256, 256, 0, stream>>>(
        rpb + (size_t)blk*2535*NHEAD, bm);
    // LN1 + roll + window-partition gather
    ln_kernel<<<NTOK/4, 256, 0, stream>>>(resid,
        ln1g + blk*CC, ln1b + blk*CC, buf1, 1, sh);
    // QKV GEMM (q pre-scaled)
    mm_kernel<128,0><<<dim3(392,3), 256, 0, stream>>>(
        buf1, wb, 128, qkvb + blk*384, bufq, 384,
        nullptr, nullptr, QKSCALE, 0, 0);
    // attention (128 windows x 4 heads)
    attn_kernel<<<NWIN*NHEAD, 256, 0, stream>>>(bufq, bm, buf1, sh);
    // proj + reverse/roll-back scatter + residual -> outf
    mm_kernel<128,2><<<dim3(392,1), 256, 0, stream>>>(
        buf1, wb+49152, 128, projb + blk*CC, nullptr, 0,
        outf, resid, 1.f, sh, 0);
    // LN2
    ln_kernel<<<NTOK/4, 256, 0, stream>>>(outf,
        ln2g + blk*CC, ln2b + blk*CC, buf1, 0, 0);
    // MLP in 2 column-halves of 256 (hidden half reuses bufq)
    for (int h = 0; h < 2; ++h){
      mm_kernel<128,1><<<dim3(392,2), 256, 0, stream>>>(
          buf1, wb + 65536 + (size_t)h*256*128, 128,
          fc1b + blk*512 + h*256, bufq, 256,
          nullptr, nullptr, 1.f, 0, 0);
      mm_kernel<256,3><<<dim3(392,1), 256, 0, stream>>>(
          bufq, wb + 131072 + h*256, 512,
          fc2b + blk*CC, nullptr, 0,
          outf, nullptr, 1.f, 0, h==0 ? 1 : 0);
    }
  }
}

// Round 7
// 555.615 us; speedup vs baseline: 4.6786x; 1.0879x over previous
//
#include <hip/hip_runtime.h>
#include <hip/hip_bf16.h>
#include <math.h>

// VideoSwinBasicLayer: 2 swin blocks (W-MSA, SW-MSA) on (1,16,56,56,128), NH=4,
// window (8,7,7) -> L=392, nW=128, shift (4,3,3), HID=512. IO f32.
// R7: mm_kernel -> global_load_lds(16B) staging, unpadded [128][32] LDS tiles;
// attn: P-buffer XOR swizzle (conflict-free) + next-step bm/K prefetch.
// ws: buf1 12.85MB | bufq 38.5MB | wtsT 0.79MB | bm 10.44MB = 62.6MB.

#define NTOK 50176   // 16*56*56
#define CC   128
#define LL   392
#define NWIN 128
#define NHEAD 4
#define HDIM 32
#define QKSCALE 0.17677669529663687f  // 32^-0.5

// attention LDS layout (u16 units)
#define KSTRIDE 40
#define KOFF    0             // K: 416 x KSTRIDE  = 16640 u16
#define VSTRIDE 424
#define VOFF    16640         // V_T: 32 x VSTRIDE = 13568 u16
#define POFF    30208         // P: 4 waves x 512  = 2048 u16 (XOR-swizzled blocks)
#define LDS_U16 32256         // 64512 B

#define BM_PER_HEAD (13*16*392)            // u32 per (cls,head) slice
#define BM_TOTAL    (8*4*BM_PER_HEAD)      // 10.44 MB

typedef unsigned short u16;
typedef unsigned int   u32;
typedef unsigned long long u64;
typedef __attribute__((ext_vector_type(8))) short short8;
typedef __attribute__((ext_vector_type(4))) float f32x4;

// async global->LDS, 16B per lane; LDS dest = wave-uniform base + lane*16.
#define GLDS(gp, lp) __builtin_amdgcn_global_load_lds( \
    (const __attribute__((address_space(1))) void*)(gp), \
    (__attribute__((address_space(3))) void*)(lp), 16, 0, 0)

__device__ __forceinline__ float b2f_lo(u32 u){ return __uint_as_float(u<<16); }
__device__ __forceinline__ float b2f_hi(u32 u){ return __uint_as_float(u & 0xffff0000u); }
__device__ __forceinline__ u16 f2b(float f){
  __hip_bfloat16 h = __float2bfloat16(f);
  return *reinterpret_cast<u16*>(&h);
}

// window-ordered row r -> flat token position (roll(+shift) both directions).
__device__ __forceinline__ int row_to_pos(int r, int shifted){
  int w = r / LL, t = r - w*LL;
  int wd = w >> 6, wh = (w >> 3) & 7, ww = w & 7;
  int td = t / 49, rem = t - td*49, th = rem / 7, tw = rem - th*7;
  int d = wd*8 + td, h = wh*7 + th, x = ww*7 + tw;
  if (shifted){ d = (d+4)&15; h += 3; if (h>=56) h-=56; x += 3; if (x>=56) x-=56; }
  return (d*56 + h)*56 + x;
}

// LayerNorm over C=128 (f32 src), bf16 out. One wave per row.
__global__ __launch_bounds__(256) void ln_kernel(
    const float* __restrict__ xf, const float* __restrict__ g,
    const float* __restrict__ b, u16* __restrict__ out, int do_map, int shifted)
{
  int wave = threadIdx.x >> 6, lane = threadIdx.x & 63;
  int r = blockIdx.x*4 + wave;
  int pos = do_map ? row_to_pos(r, shifted) : r;
  long src = (long)pos * CC;
  float v0 = xf[src+lane], v1 = xf[src+64+lane];
  float s = v0+v1, ss = v0*v0 + v1*v1;
  #pragma unroll
  for (int o=32; o>0; o>>=1){ s += __shfl_xor(s,o); ss += __shfl_xor(ss,o); }
  float mean = s*(1.f/CC);
  float var  = ss*(1.f/CC) - mean*mean;
  float rstd = rsqrtf(var + 1e-5f);
  long dst = (long)r*CC;
  out[dst + lane]      = f2b((v0-mean)*rstd*g[lane]    + b[lane]);
  out[dst + 64 + lane] = f2b((v1-mean)*rstd*g[64+lane] + b[64+lane]);
}

// Transpose+convert weights: in f32 [Kd][Nd] row-major -> out bf16 [Nd][Kd].
__global__ __launch_bounds__(256) void wt_kernel(
    const float* __restrict__ in, u16* __restrict__ out, int Kd, int Nd, int total)
{
  int t = blockIdx.x*256 + threadIdx.x;
  if (t >= total) return;
  int n = t / Kd, k = t - n*Kd;
  out[t] = f2b(in[k*Nd + n]);
}

// Packed bias(+mask) table: bm[cls][h][s][jj][i] u32 = (bf16 v(j=s*32+jj, i),
// bf16 v(j+16, i)).  v = rpb-bias - 100*maskneq(cls);  j>=392 -> -1e30.
__global__ __launch_bounds__(256) void biasm_kernel(
    const float* __restrict__ rpb, u32* __restrict__ bm)
{
  int t = blockIdx.x*256 + threadIdx.x;
  if (t >= BM_TOTAL) return;
  int i = t % 392; int rest = t / 392;
  int jj = rest % 16; rest /= 16;
  int s  = rest % 13; rest /= 13;
  int h  = rest % 4;  int cls = rest / 4;
  int tdi=i/49, rmi=i-tdi*49, thi=rmi/7, twi=rmi-thi*7;
  u32 pack = 0;
  #pragma unroll
  for (int half=0; half<2; half++){
    int j = s*32 + jj + half*16;
    float v = -1e30f;
    if (j < LL){
      int tdj=j/49, rmj=j-tdj*49, thj=rmj/7, twj=rmj-thj*7;
      int idx = (tdi-tdj)*169 + (thi-thj)*13 + (twi-twj) + 1267;
      v = rpb[idx*NHEAD + h];
      bool neq = ((cls&4) && ((tdi<4) != (tdj<4)))
              || ((cls&2) && ((thi<4) != (thj<4)))
              || ((cls&1) && ((twi<4) != (twj<4)));
      if (neq) v -= 100.f;
    }
    pack |= ((u32)f2b(v)) << (16*half);
  }
  bm[t] = pack;
}

// MFMA GEMM, m97-style staging: C[128x128] = A[rows x KD](bf16) @ Wt^T (Wt [N][K]
// bf16). Unpadded LDS [128][32]; global_load_lds width 16 (4 issues/wave/K-iter).
// EPI: 0 = (+bias)*scale -> bf16 (qkv; scale only blockIdx.y==0)
//      1 = +bias, GELU -> bf16 | 2 = +bias, scatter, +Res -> f32 | 3 = accum f32
template<int KD, int EPI>
__global__ __launch_bounds__(256) void mm_kernel(
    const u16* __restrict__ A, const u16* __restrict__ Wt, int ldw,
    const float* __restrict__ bias, u16* __restrict__ OutB, int ldo,
    float* __restrict__ OutF, const float* __restrict__ Res,
    float scaleq, int shifted, int use_bias)
{
  __shared__ __align__(16) u16 As[128*32];
  __shared__ __align__(16) u16 Bs[128*32];
  const int tid = threadIdx.x, lane = tid & 63, wv = tid >> 6;
  const int quad = lane >> 4, l15 = lane & 15;
  const int rh = wv >> 1, ch = wv & 1;
  const int r0 = blockIdx.x * 128, n0 = blockIdx.y * 128;
  const int srow = lane >> 2, spart = (lane & 3) * 8;  // staging: 16 rows/issue

  f32x4 acc[4][4] = {};

  for (int kt = 0; kt < KD/32; kt++){
    const int k0 = kt*32;
    #pragma unroll
    for (int t=0;t<2;t++){
      const int rowbase = wv*32 + t*16;
      GLDS(&A [(long)(r0 + rowbase + srow)*KD  + k0 + spart], &As[rowbase*32]);
      GLDS(&Wt[(long)(n0 + rowbase + srow)*ldw + k0 + spart], &Bs[rowbase*32]);
    }
    __syncthreads();
    short8 af[4], bf[4];
    #pragma unroll
    for (int rt=0;rt<4;rt++)
      af[rt] = *reinterpret_cast<const short8*>(&As[(rh*64 + rt*16 + l15)*32 + quad*8]);
    #pragma unroll
    for (int ct=0;ct<4;ct++)
      bf[ct] = *reinterpret_cast<const short8*>(&Bs[(ch*64 + ct*16 + l15)*32 + quad*8]);
    #pragma unroll
    for (int rt=0;rt<4;rt++)
      #pragma unroll
      for (int ct=0;ct<4;ct++)
        acc[rt][ct] = __builtin_amdgcn_mfma_f32_16x16x32_bf16(af[rt], bf[ct], acc[rt][ct], 0,0,0);
    __syncthreads();
  }

  #pragma unroll
  for (int rt=0;rt<4;rt++){
    #pragma unroll
    for (int rr=0;rr<4;rr++){
      const int row_g = r0 + rh*64 + rt*16 + quad*4 + rr;
      long pos = 0;
      if (EPI == 2) pos = (long)row_to_pos(row_g, shifted) * CC;
      #pragma unroll
      for (int ct=0;ct<4;ct++){
        const int col_g = n0 + ch*64 + ct*16 + l15;
        float v = acc[rt][ct][rr];
        if (EPI == 0){
          float sc = (blockIdx.y == 0) ? scaleq : 1.f;
          v = (v + bias[col_g]) * sc;
          OutB[(long)row_g*ldo + col_g] = f2b(v);
        } else if (EPI == 1){
          v += bias[col_g];
          v = 0.5f*v*(1.f + erff(v*0.70710678118654752f));
          OutB[(long)row_g*ldo + col_g] = f2b(v);
        } else if (EPI == 2){
          OutF[pos + col_g] = Res[pos + col_g] + v + bias[col_g];
        } else {
          float o = OutF[(long)row_g*CC + col_g] + v;
          if (use_bias) o += bias[col_g];
          OutF[(long)row_g*CC + col_g] = o;
        }
      }
    }
  }
}

// MFMA flash attention, S^T orientation. One block per (window, head); 4 waves
// x 16-row q-tiles. Scalar softmax state (q-row = lane&15). Packed bias+mask
// table prefetched one step ahead (with next K-frags). P round-trip through
// XOR-swizzled wave-private LDS (conflict-free b64 writes / b128 read).
__global__ __launch_bounds__(256) void attn_kernel(
    const u16* __restrict__ qkv, const u32* __restrict__ bm,
    u16* __restrict__ out, int shifted)
{
  __shared__ __align__(16) u16 lds[LDS_U16];

  const int w = blockIdx.x >> 2, head = blockIdx.x & 3;
  const int tid = threadIdx.x, lane = tid & 63, wave = tid >> 6;
  const int quad = lane >> 4, l15 = lane & 15;
  const long qkvbase = (long)w * LL * 384;
  const int wd = w>>6, wh = (w>>3)&7, ww = w&7;
  const int cls = shifted ? (((wd!=0)?4:0) | ((wh==7)?2:0) | ((ww==7)?1:0)) : 0;
  const u32* __restrict__ bmh = bm + (size_t)(cls*NHEAD + head)*BM_PER_HEAD;
  const int pbase = POFF + wave*512;
  const int pwb0 = ((quad>>1)     ^ (l15&3))*8 + (quad&1)*4;  // w0 phys offset
  const int pwb1 = ((2+(quad>>1)) ^ (l15&3))*8 + (quad&1)*4;  // w1 phys offset

  // stage K (rows 392..415 zeroed)
  for (int idx = tid; idx < 416*4; idx += 256){
    int key = idx >> 2, part = idx & 3;
    short8 val = {0,0,0,0,0,0,0,0};
    if (key < LL)
      val = *reinterpret_cast<const short8*>(&qkv[qkvbase + (long)key*384 + 128 + head*HDIM + part*8]);
    *reinterpret_cast<short8*>(&lds[KOFF + key*KSTRIDE + part*8]) = val;
  }
  // stage V transposed (keys 392..415 zeroed)
  for (int idx = tid; idx < 416*32; idx += 256){
    int key = idx >> 5, d = idx & 31;
    u16 v = (key < LL) ? qkv[qkvbase + (long)key*384 + 256 + head*HDIM + d] : (u16)0;
    lds[VOFF + d*VSTRIDE + key] = v;
  }
  __syncthreads();

  for (int qt = wave; qt < 25; qt += 4){
    int iq = qt*16 + l15; if (iq > LL-1) iq = LL-1;
    short8 qf = *reinterpret_cast<const short8*>(&qkv[qkvbase + (long)iq*384 + head*HDIM + quad*8]);

    float m_s = -1e30f, l_s = 0.f;
    f32x4 oc0 = {0.f,0.f,0.f,0.f}, oc1 = {0.f,0.f,0.f,0.f};

    // prefetch step 0
    u32 bmv[4];
    {
      const u32* bp = &bmh[iq];
      #pragma unroll
      for (int r=0;r<4;r++) bmv[r] = bp[(quad*4+r)*392];
    }
    short8 kf0 = *reinterpret_cast<const short8*>(&lds[KOFF + l15*KSTRIDE + quad*8]);
    short8 kf1 = *reinterpret_cast<const short8*>(&lds[KOFF + (16 + l15)*KSTRIDE + quad*8]);

    for (int s = 0; s < 13; s++){
      const int kbase = s*32;
      // prefetch next step's bias+mask (global) and K-frags (LDS)
      u32 bmn[4] = {};
      short8 kn0 = {}, kn1 = {};
      if (s < 12){
        const u32* bp = &bmh[(size_t)((s+1)*16)*392 + iq];
        #pragma unroll
        for (int r=0;r<4;r++) bmn[r] = bp[(quad*4+r)*392];
        kn0 = *reinterpret_cast<const short8*>(&lds[KOFF + (kbase + 32 + l15)*KSTRIDE + quad*8]);
        kn1 = *reinterpret_cast<const short8*>(&lds[KOFF + (kbase + 48 + l15)*KSTRIDE + quad*8]);
      }

      f32x4 z = {0.f,0.f,0.f,0.f};
      f32x4 c0 = __builtin_amdgcn_mfma_f32_16x16x32_bf16(kf0, qf, z, 0,0,0);
      f32x4 c1 = __builtin_amdgcn_mfma_f32_16x16x32_bf16(kf1, qf, z, 0,0,0);
      // c0[r]: S[qrow=iq][key=kbase+quad*4+r]; c1[r]: key +16

      float s0[4], s1[4];
      float mt = -1e30f;
      #pragma unroll
      for (int r=0;r<4;r++){
        s0[r] = c0[r] + b2f_lo(bmv[r]);
        s1[r] = c1[r] + b2f_hi(bmv[r]);
        mt = fmaxf(mt, fmaxf(s0[r], s1[r]));
      }
      mt = fmaxf(mt, __shfl_xor(mt, 16));
      mt = fmaxf(mt, __shfl_xor(mt, 32));
      float mn = fmaxf(m_s, mt);
      float al = __expf(m_s - mn);
      m_s = mn;

      float rs = 0.f;
      u16 pb0[4], pb1[4];
      #pragma unroll
      for (int r=0;r<4;r++){
        float p0 = __expf(s0[r] - mn);
        float p1 = __expf(s1[r] - mn);
        rs += p0 + p1;
        pb0[r] = f2b(p0); pb1[r] = f2b(p1);
      }
      rs += __shfl_xor(rs, 16);
      rs += __shfl_xor(rs, 32);
      l_s = l_s*al + rs;

      // P -> wave-private LDS (XOR-swizzled 8-u16 blocks, conflict-free)
      u64 w0 = (u64)pb0[0] | ((u64)pb0[1]<<16) | ((u64)pb0[2]<<32) | ((u64)pb0[3]<<48);
      u64 w1 = (u64)pb1[0] | ((u64)pb1[1]<<16) | ((u64)pb1[2]<<32) | ((u64)pb1[3]<<48);
      *reinterpret_cast<u64*>(&lds[pbase + l15*32 + pwb0]) = w0;
      *reinterpret_cast<u64*>(&lds[pbase + l15*32 + pwb1]) = w1;

      // rescale O (C-layout rows = q-rows quad*4+r)
      #pragma unroll
      for (int r=0;r<4;r++){
        float alr = __shfl(al, quad*4 + r);
        oc0[r] *= alr; oc1[r] *= alr;
      }

      short8 pa  = *reinterpret_cast<const short8*>(&lds[pbase + l15*32 + ((quad^(l15&3))*8)]);
      short8 vb0 = *reinterpret_cast<const short8*>(&lds[VOFF + l15*VSTRIDE + kbase + quad*8]);
      short8 vb1 = *reinterpret_cast<const short8*>(&lds[VOFF + (16+l15)*VSTRIDE + kbase + quad*8]);
      oc0 = __builtin_amdgcn_mfma_f32_16x16x32_bf16(pa, vb0, oc0, 0,0,0);
      oc1 = __builtin_amdgcn_mfma_f32_16x16x32_bf16(pa, vb1, oc1, 0,0,0);

      #pragma unroll
      for (int r=0;r<4;r++) bmv[r] = bmn[r];
      kf0 = kn0; kf1 = kn1;
    }

    float inv = 1.f / l_s;
    #pragma unroll
    for (int r=0;r<4;r++){
      float invr = __shfl(inv, quad*4 + r);
      int i = qt*16 + quad*4 + r;
      if (i < LL){
        long o = ((long)(w*LL + i))*CC + head*HDIM;
        out[o + l15]      = f2b(oc0[r]*invr);
        out[o + 16 + l15] = f2b(oc1[r]*invr);
      }
    }
  }
}

extern "C" void kernel_launch(void* const* d_in, const int* in_sizes, int n_in,
                              void* d_out, int out_size, void* d_ws, size_t ws_size,
                              hipStream_t stream)
{
  const float* x     = (const float*)d_in[0];
  const float* ln1g  = (const float*)d_in[1];
  const float* ln1b  = (const float*)d_in[2];
  const float* qkvw  = (const float*)d_in[3];
  const float* qkvb  = (const float*)d_in[4];
  const float* rpb   = (const float*)d_in[5];
  const float* projw = (const float*)d_in[6];
  const float* projb = (const float*)d_in[7];
  const float* ln2g  = (const float*)d_in[8];
  const float* ln2b  = (const float*)d_in[9];
  const float* fc1w  = (const float*)d_in[10];
  const float* fc1b  = (const float*)d_in[11];
  const float* fc2w  = (const float*)d_in[12];
  const float* fc2b  = (const float*)d_in[13];
  float* outf = (float*)d_out;                  // f32 residual stream / output

  u16* buf1 = (u16*)d_ws;                       // bf16 act, NTOK*128
  u16* bufq = buf1 + (size_t)NTOK*CC;           // bf16 qkv / mlp hidden half
  u16* wts  = bufq + (size_t)NTOK*384;          // transposed bf16 weights
  u32* bm   = (u32*)(wts + 393216);             // packed bias+mask table

  for (int blk = 0; blk < 2; ++blk){
    u16* wb = wts + (size_t)blk*196608;
    wt_kernel<<<(49152+255)/256, 256, 0, stream>>>(qkvw + (size_t)blk*128*384, wb,          128, 384, 49152);
    wt_kernel<<<(16384+255)/256, 256, 0, stream>>>(projw + (size_t)blk*128*128, wb+49152,   128, 128, 16384);
    wt_kernel<<<(65536+255)/256, 256, 0, stream>>>(fc1w  + (size_t)blk*128*512, wb+65536,   128, 512, 65536);
    wt_kernel<<<(65536+255)/256, 256, 0, stream>>>(fc2w  + (size_t)blk*512*128, wb+131072,  512, 128, 65536);
  }

  for (int blk = 0; blk < 2; ++blk){
    const int sh = blk;
    const float* resid = (blk==0) ? x : outf;
    u16* wb = wts + (size_t)blk*196608;

    biasm_kernel<<<(BM_TOTAL+255)/256, 256, 0, stream>>>(
        rpb + (size_t)blk*2535*NHEAD, bm);
    // LN1 + roll + window-partition gather
    ln_kernel<<<NTOK/4, 256, 0, stream>>>(resid,
        ln1g + blk*CC, ln1b + blk*CC, buf1, 1, sh);
    // QKV GEMM (q pre-scaled)
    mm_kernel<128,0><<<dim3(392,3), 256, 0, stream>>>(
        buf1, wb, 128, qkvb + blk*384, bufq, 384,
        nullptr, nullptr, QKSCALE, 0, 0);
    // attention (128 windows x 4 heads)
    attn_kernel<<<NWIN*NHEAD, 256, 0, stream>>>(bufq, bm, buf1, sh);
    // proj + reverse/roll-back scatter + residual -> outf
    mm_kernel<128,2><<<dim3(392,1), 256, 0, stream>>>(
        buf1, wb+49152, 128, projb + blk*CC, nullptr, 0,
        outf, resid, 1.f, sh, 0);
    // LN2
    ln_kernel<<<NTOK/4, 256, 0, stream>>>(outf,
        ln2g + blk*CC, ln2b + blk*CC, buf1, 0, 0);
    // MLP in 2 column-halves of 256 (hidden half reuses bufq)
    for (int h = 0; h < 2; ++h){
      mm_kernel<128,1><<<dim3(392,2), 256, 0, stream>>>(
          buf1, wb + 65536 + (size_t)h*256*128, 128,
          fc1b + blk*512 + h*256, bufq, 256,
          nullptr, nullptr, 1.f, 0, 0);
      mm_kernel<256,3><<<dim3(392,1), 256, 0, stream>>>(
          bufq, wb + 131072 + h*256, 512,
          fc2b + blk*CC, nullptr, 0,
          outf, nullptr, 1.f, 0, h==0 ? 1 : 0);
    }
  }
}